// Round 3
// baseline (1104.787 us; speedup 1.0000x reference)
//
#include <hip/hip_runtime.h>
#include <hip/hip_bf16.h>

typedef __hip_bfloat16 bf16;
typedef __attribute__((ext_vector_type(8))) short short8;   // 8 bf16 = 4 VGPRs (MFMA A/B frag)
typedef __attribute__((ext_vector_type(4))) float f32x4;    // MFMA C/D frag

#define S_TOK   2048
#define NROWS   4096        // B*S
#define NH      16
#define QKD     192
#define NOPE_   128
#define ROPE_   64
#define VDIM_   128
#define RANK    512
#define SCALE_F 0.07216878364870323f   // 192^-0.5
#define NEG_BIG -3.0e38f
#define DEFER_THR 8.0f

__device__ __forceinline__ float bl(unsigned u){ union{unsigned i; float f;} t; t.i = u << 16; return t.f; }
__device__ __forceinline__ float bh(unsigned u){ union{unsigned i; float f;} t; t.i = u & 0xffff0000u; return t.f; }
__device__ __forceinline__ unsigned short f2b(float f){
  bf16 h = __float2bfloat16(f);
  return *reinterpret_cast<unsigned short*>(&h);
}
__device__ __forceinline__ void store4(bf16* p, float a, float b, float c, float d){
  ushort4 u; u.x=f2b(a); u.y=f2b(b); u.z=f2b(c); u.w=f2b(d);
  *(ushort4*)p = u;
}
union U8 { uint4 u; short8 s; };
#define MFMA16x32(a,b,c) __builtin_amdgcn_mfma_f32_16x16x32_bf16(a,b,c,0,0,0)

// async global -> LDS DMA, 16 B per lane; dest wave-uniform base + lane*16.
__device__ __forceinline__ void gload16(const unsigned short* g, unsigned short* l)
{
  __builtin_amdgcn_global_load_lds(
      (const __attribute__((address_space(1))) unsigned int*)g,
      (__attribute__((address_space(3))) unsigned int*)l,
      16, 0, 0);
}

// ---------------------------------------------------------------------------
// cvt_bf16: f32 -> bf16 elementwise (n multiple of 1024)
// ---------------------------------------------------------------------------
__global__ __launch_bounds__(256) void cvt_bf16(const float* __restrict__ src,
                                                bf16* __restrict__ dst, int n)
{
  int g = (blockIdx.x * 256 + threadIdx.x) * 4;
  if (g < n) {
    float4 v = *(const float4*)(src + g);
    store4(dst + g, v.x, v.y, v.z, v.w);
  }
}

// ---------------------------------------------------------------------------
// tr_wbk: wkv_b K-half (h, d<128, c) f32 -> wbkT (h, c, d) bf16.  grid (2,8,16)
// ---------------------------------------------------------------------------
__global__ __launch_bounds__(256) void tr_wbk(const float* __restrict__ wkvb,
                                              bf16* __restrict__ wbkT)
{
  const int d0 = blockIdx.x << 6, c0 = blockIdx.y << 6, h = blockIdx.z;
  const int tid = threadIdx.x;
  __shared__ float tile[64*65];
  #pragma unroll
  for (int j = 0; j < 16; ++j) {
    int idx = tid + j*256; int r = idx >> 6, c = idx & 63;   // r=d, c=c
    tile[r*65 + c] = wkvb[((long)(h*256 + d0 + r))*512 + c0 + c];
  }
  __syncthreads();
  #pragma unroll
  for (int j = 0; j < 16; ++j) {
    int idx = tid + j*256; int r = idx >> 6, cc = idx & 63;  // r=c, cc=d
    ((unsigned short*)wbkT)[(long)h*65536 + (long)(c0 + r)*128 + d0 + cc] = f2b(tile[cc*65 + r]);
  }
}

// ---------------------------------------------------------------------------
// wbv_cvt: wkv_b V-half (16 x 128 x 512 f32) -> bf16 (same orientation)
// ---------------------------------------------------------------------------
__global__ __launch_bounds__(256) void wbv_cvt(const float* __restrict__ wkvb,
                                               bf16* __restrict__ wbv)
{
  int g = blockIdx.x * 256 + threadIdx.x;       // 1,048,576
  int h = g >> 16, rem = g & 65535;
  ((unsigned short*)wbv)[g] = f2b(wkvb[((long)(h*256 + NOPE_))*512 + rem]);
}

// ---------------------------------------------------------------------------
// MFMA GEMM: C[M,N] = A[M,K] @ W[N,K]^T, bf16 A/W, TOUT out.
// ---------------------------------------------------------------------------
template<typename TOUT>
__global__ __launch_bounds__(256) void gemm_mfma(
    const bf16* __restrict__ A, const bf16* __restrict__ W, TOUT* __restrict__ C,
    int K, int lda, int ldw, int ldc, long azs, long wzs, long czs)
{
  A += (long)blockIdx.z * azs;
  W += (long)blockIdx.z * wzs;
  C += (long)blockIdx.z * czs;
  __shared__ __align__(16) unsigned short As[8*65*8];   // 8320 B
  __shared__ __align__(16) unsigned short Ws[8*65*8];
  const int tid = threadIdx.x;
  const int m0 = blockIdx.y << 6, n0 = blockIdx.x << 6;
  const int w = tid >> 6, lane = tid & 63;
  const int quad = lane >> 4, l16 = lane & 15;

  const int r0 = tid >> 3, c80 = tid & 7;
  const int r1 = (tid + 256) >> 3;

  f32x4 acc[4];
  #pragma unroll
  for (int i = 0; i < 4; ++i) acc[i] = (f32x4){0.f,0.f,0.f,0.f};

  for (int k0 = 0; k0 < K; k0 += 64) {
    uint4 a0 = *(const uint4*)(A + (long)(m0 + r0)*lda + k0 + c80*8);
    uint4 a1 = *(const uint4*)(A + (long)(m0 + r1)*lda + k0 + c80*8);
    uint4 w0 = *(const uint4*)(W + (long)(n0 + r0)*ldw + k0 + c80*8);
    uint4 w1 = *(const uint4*)(W + (long)(n0 + r1)*ldw + k0 + c80*8);
    __syncthreads();
    *(uint4*)(As + (c80*65 + r0)*8) = a0;
    *(uint4*)(As + (c80*65 + r1)*8) = a1;
    *(uint4*)(Ws + (c80*65 + r0)*8) = w0;
    *(uint4*)(Ws + (c80*65 + r1)*8) = w1;
    __syncthreads();
    #pragma unroll
    for (int kc = 0; kc < 2; ++kc) {
      const int kcq = kc*4 + quad;
      U8 af; af.u = *(const uint4*)(As + (kcq*65 + w*16 + l16)*8);
      #pragma unroll
      for (int nt = 0; nt < 4; ++nt) {
        U8 bf_; bf_.u = *(const uint4*)(Ws + (kcq*65 + nt*16 + l16)*8);
        acc[nt] = MFMA16x32(af.s, bf_.s, acc[nt]);
      }
    }
  }
  #pragma unroll
  for (int nt = 0; nt < 4; ++nt) {
    #pragma unroll
    for (int i = 0; i < 4; ++i) {
      long row = m0 + w*16 + quad*4 + i;
      TOUT v;
      if constexpr (sizeof(TOUT) == 2) v = __float2bfloat16(acc[nt][i]);
      else                             v = acc[nt][i];
      C[row*ldc + n0 + nt*16 + l16] = v;
    }
  }
}

// ---------------------------------------------------------------------------
// kvprep (bf16 in): RMSNorm first 512 -> ckv (bf16), RoPE last 64 -> kpe (bf16)
// ---------------------------------------------------------------------------
__global__ __launch_bounds__(64) void kvprep(
    const bf16* __restrict__ kvbuf, const float* __restrict__ wnorm,
    const float* __restrict__ cosb, const float* __restrict__ sinb,
    bf16* __restrict__ ckv, bf16* __restrict__ kpe)
{
  const int row = blockIdx.x;
  const int s = row & (S_TOK - 1);
  const int lane = threadIdx.x;
  const unsigned short* kr = (const unsigned short*)kvbuf + (long)row * 576;
  uint4 u = *(const uint4*)(kr + lane*8);
  float v[8] = { bl(u.x), bh(u.x), bl(u.y), bh(u.y), bl(u.z), bh(u.z), bl(u.w), bh(u.w) };
  float ss = 0.f;
  #pragma unroll
  for (int j = 0; j < 8; ++j) ss += v[j]*v[j];
  #pragma unroll
  for (int off = 32; off > 0; off >>= 1) ss += __shfl_down(ss, off);
  ss = __shfl(ss, 0);
  const float scl = rsqrtf(ss * (1.0f/512.0f) + 1e-6f);
  float4 w0 = *(const float4*)(wnorm + lane*8);
  float4 w1 = *(const float4*)(wnorm + lane*8 + 4);
  bf16* cd = ckv + (long)row*512 + lane*8;
  store4(cd,   v[0]*scl*w0.x, v[1]*scl*w0.y, v[2]*scl*w0.z, v[3]*scl*w0.w);
  store4(cd+4, v[4]*scl*w1.x, v[5]*scl*w1.y, v[6]*scl*w1.z, v[7]*scl*w1.w);
  if (lane < 32) {
    unsigned pe = *(const unsigned*)(kr + 512 + 2*lane);
    float xe = bl(pe), xo = bh(pe);
    float c = cosb[s*32 + lane], sn = sinb[s*32 + lane];
    ushort2 o; o.x = f2b(xe*c - xo*sn); o.y = f2b(xe*sn + xo*c);
    *(ushort2*)((unsigned short*)kpe + (long)row*64 + 2*lane) = o;
  }
}

// ---------------------------------------------------------------------------
// ropeq (bf16 in): RoPE q_pe slice of qbuf -> qpe (bf16, 4096 x 16*64)
// ---------------------------------------------------------------------------
__global__ __launch_bounds__(256) void ropeq(
    const bf16* __restrict__ qbuf, const float* __restrict__ cosb,
    const float* __restrict__ sinb, bf16* __restrict__ qpe)
{
  int gid = blockIdx.x * 256 + threadIdx.x;       // 4096*16*32
  int row = gid >> 9; int rem = gid & 511;
  int h = rem >> 5, i = rem & 31;
  int s = row & (S_TOK - 1);
  unsigned pp = *(const unsigned*)((const unsigned short*)qbuf + (long)row*3072 + h*QKD + NOPE_ + 2*i);
  float xe = bl(pp), xo = bh(pp);
  float c = cosb[s*32 + i], sn = sinb[s*32 + i];
  ushort2 u; u.x = f2b(xe*c - xo*sn); u.y = f2b(xe*sn + xo*c);
  *(ushort2*)((unsigned short*)qpe + (long)row*1024 + h*64 + 2*i) = u;
}

// ---------------------------------------------------------------------------
// tr64: ckv (b, t, c) -> ckvT TILED+SWIZZLED: granule (per b, per 32-tok tile)
//   g(tile, c, tg) = tile*2048 + c*4 + (tg ^ ((c>>1)&3)),  tg = (t&31)>>3,
// element byte within granule = (t&7)*2.  The XOR spreads the attention PV
// B-frag reads (fixed quad=tg, varying c) over 8 distinct bank groups.
// DMA to LDS stays a pure linear copy (swizzle on source+read, dest linear).
// ---------------------------------------------------------------------------
__global__ __launch_bounds__(256) void tr64(const bf16* __restrict__ ckv,
                                            bf16* __restrict__ ckvT)
{
  const int t0 = blockIdx.x << 6, c0 = blockIdx.y << 6, b = blockIdx.z;
  const int tid = threadIdx.x;
  __shared__ unsigned short tile[64*65];
  const unsigned short* src = (const unsigned short*)ckv + (long)b*S_TOK*512;
  #pragma unroll
  for (int j = 0; j < 16; ++j) {
    int idx = tid + j*256; int r = idx >> 6, c = idx & 63;
    tile[r*65 + c] = src[(long)(t0+r)*512 + c0 + c];
  }
  __syncthreads();
  unsigned short* dst = (unsigned short*)ckvT + (long)b*512*S_TOK;
  #pragma unroll
  for (int j = 0; j < 16; ++j) {
    int idx = tid + j*256; int r = idx >> 6, t = idx & 63;   // r: c offset, t: token offset
    int tt = t0 + t;
    int c  = c0 + r;
    long g = (long)(tt >> 5)*2048 + (long)c*4 + (((tt & 31) >> 3) ^ ((c >> 1) & 3));
    dst[g*8 + (tt & 7)] = tile[t*65 + r];
  }
}

// ---------------------------------------------------------------------------
// MFMA flash attention v6 — round-1 verified barrier structure (DMA staging +
// __syncthreads), plus: swizzled V^T (bank-conflict-free PV), masked-tile
// second-half skip, defer-max softmax, XCD-aware block remap.
// grid = 512; physical block -> (b = xcd>>2) so each XCD L2 caches one batch.
// ---------------------------------------------------------------------------
__global__ __launch_bounds__(256, 2) void attn_mfma(
    const bf16* __restrict__ qlat,   // (4096, 16*512)
    const bf16* __restrict__ qpe,    // (4096, 16*64)
    const bf16* __restrict__ ckv,    // (4096, 512)
    const bf16* __restrict__ kpe,    // (4096, 64)
    const bf16* __restrict__ ckvT,   // (B, 64 tiles, 512, 32) swizzled
    const bf16* __restrict__ wbv,    // (16, 128, 512)
    bf16* __restrict__ obuf)         // (4096, 2048) bf16
{
  // XCD-aware remap: phys idx -> (b, h, qp).  xcd = phys & 7 (round-robin
  // dispatch); xcd 0-3 take b=0, 4-7 take b=1.  Bijective over [0,512).
  const int phys = blockIdx.x;
  const int b  = (phys & 7) >> 2;
  const int r_ = ((phys & 3) << 6) | (phys >> 3);   // [0,256)
  const int qp = r_ & 15;
  const int h  = r_ >> 4;
  const int tid = threadIdx.x;
  const int w = tid >> 6, lane = tid & 63;
  const int quad = lane >> 4, l16 = lane & 15;

  __shared__ __align__(16) unsigned short smem[4352 * 8];    // 69,632 B
  __shared__ __align__(16) unsigned short P_s[4 * 16 * 40];  //  5,120 B

  const unsigned short* ckv_b  = (const unsigned short*)ckv  + (long)b*S_TOK*512;
  const unsigned short* kpe_b  = (const unsigned short*)kpe  + (long)b*S_TOK*64;
  const unsigned short* ckvT_b = (const unsigned short*)ckvT + (long)b*512*S_TOK;
  unsigned short* Pw = P_s + w*640;

  #pragma unroll 1
  for (int half = 0; half < 2; ++half) {
    const int qt = half ? qp : (31 - qp);      // big q-tile first
    const int q0 = qt << 6;

    // ---- Q fragments: A[m=l16][k=quad*8+j], 18 K-chunks (512 lat + 64 pe)
    const long qrow = (long)b*S_TOK + q0 + w*16 + l16;
    short8 qf[18];
    {
      const unsigned short* qlp = (const unsigned short*)qlat + qrow*8192 + h*512 + quad*8;
      const unsigned short* qpp = (const unsigned short*)qpe  + qrow*1024 + h*64  + quad*8;
      #pragma unroll
      for (int kc = 0; kc < 16; ++kc) { U8 t; t.u = *(const uint4*)(qlp + kc*32); qf[kc] = t.s; }
      { U8 t; t.u = *(const uint4*)(qpp);      qf[16] = t.s; }
      { U8 t; t.u = *(const uint4*)(qpp + 32); qf[17] = t.s; }
    }

    f32x4 acc[32];
    #pragma unroll
    for (int i = 0; i < 32; ++i) acc[i] = (f32x4){0.f,0.f,0.f,0.f};
    float mi[4] = {NEG_BIG,NEG_BIG,NEG_BIG,NEG_BIG};
    float li[4] = {0.f,0.f,0.f,0.f};

    const int myqmax = q0 + w*16 + 15;
    const int ntiles = (q0 >> 5) + 2;

    for (int tile = 0; tile < ntiles; ++tile) {
      const int t0 = tile << 5;
      // ---- async-stage K-tile: all coalesced 16B-per-lane DMA ----
      #pragma unroll
      for (int j = 0; j < 8; ++j) {                       // ckv: 1 row / wave-instr
        const int u = tid + j*256;
        const int t = u >> 6, c8 = (u & 63) ^ (t & 7);
        gload16(ckv_b + (long)(t0 + t)*512 + c8*8, smem + (j*256 + w*64)*8);
      }
      { const int t = tid >> 3, c8p = (tid & 7) ^ (t & 7); // kpe: 8 rows / wave-instr
        gload16(kpe_b + (long)(t0 + t)*64 + c8p*8, smem + (2048 + w*64)*8); }
      {
        const unsigned short* vt = ckvT_b + (long)tile * 16384;  // V^T: pure linear
        #pragma unroll
        for (int j = 0; j < 8; ++j)
          gload16(vt + (long)(tid + j*256)*8, smem + (2304 + j*256 + w*64)*8);
      }
      __syncthreads();   // drains vmcnt: DMA complete, previous reads done

      const bool active = (t0 <= myqmax);
      const bool act1   = (t0 + 16 <= myqmax);
      if (active) {
        // ---- scores: two 16x16 C-tiles (second skipped if fully masked) ----
        f32x4 sc0 = (f32x4){0.f,0.f,0.f,0.f}, sc1 = sc0;
        #pragma unroll
        for (int kc = 0; kc < 18; ++kc) {
          const int kcq = kc*4 + quad;
          int g0, g1;
          if (kc < 16) {
            g0 = l16*64        + (kcq ^ (l16 & 7));
            g1 = (16+l16)*64   + (kcq ^ (l16 & 7));
          } else {
            g0 = 2048 + l16*8      + ((kcq & 7) ^ (l16 & 7));
            g1 = 2048 + (16+l16)*8 + ((kcq & 7) ^ (l16 & 7));
          }
          U8 b0; b0.u = *(const uint4*)(smem + g0*8);
          sc0 = MFMA16x32(qf[kc], b0.s, sc0);
          if (act1) {
            U8 b1; b1.u = *(const uint4*)(smem + g1*8);
            sc1 = MFMA16x32(qf[kc], b1.s, sc1);
          }
        }
        // ---- online softmax with defer-max (THR bounds P by e^THR) ----
        float s0[4], s1[4], tm[4];
        #pragma unroll
        for (int i = 0; i < 4; ++i) {
          int qg = q0 + w*16 + quad*4 + i;
          s0[i] = (t0 + l16 <= qg) ? sc0[i]*SCALE_F : NEG_BIG;
          s1[i] = (act1 && (t0 + 16 + l16 <= qg)) ? sc1[i]*SCALE_F : NEG_BIG;
          tm[i] = fmaxf(s0[i], s1[i]);
        }
        #pragma unroll
        for (int d = 1; d < 16; d <<= 1) {
          #pragma unroll
          for (int i = 0; i < 4; ++i) tm[i] = fmaxf(tm[i], __shfl_xor(tm[i], d));
        }
        bool small = (tm[0] - mi[0] <= DEFER_THR) && (tm[1] - mi[1] <= DEFER_THR)
                  && (tm[2] - mi[2] <= DEFER_THR) && (tm[3] - mi[3] <= DEFER_THR);
        if (!__all(small)) {
          float al[4];
          #pragma unroll
          for (int i = 0; i < 4; ++i) {
            float mx = fmaxf(mi[i], tm[i]);
            al[i] = __expf(mi[i] - mx);
            mi[i] = mx;
            li[i] *= al[i];
          }
          #pragma unroll
          for (int nt = 0; nt < 32; ++nt) {
            #pragma unroll
            for (int i = 0; i < 4; ++i) acc[nt][i] *= al[i];
          }
        }
        float rs[4];
        #pragma unroll
        for (int i = 0; i < 4; ++i) {
          float p0 = __expf(s0[i] - mi[i]);
          float p1 = __expf(s1[i] - mi[i]);
          rs[i] = p0 + p1;
          Pw[(quad*4+i)*40 + l16]      = f2b(p0);
          Pw[(quad*4+i)*40 + 16 + l16] = f2b(p1);
        }
        #pragma unroll
        for (int d = 1; d < 16; d <<= 1) {
          #pragma unroll
          for (int i = 0; i < 4; ++i) rs[i] += __shfl_xor(rs[i], d);
        }
        #pragma unroll
        for (int i = 0; i < 4; ++i) li[i] += rs[i];
        // ---- PV: A = P (LDS roundtrip), B = V^T tile (swizzled) ----
        U8 ap; ap.u = *(const uint4*)(Pw + l16*40 + quad*8);
        #pragma unroll
        for (int nt = 0; nt < 32; ++nt) {
          const int c = nt*16 + l16;
          U8 bv; bv.u = *(const uint4*)(smem + (2304 + c*4 + (quad ^ ((c >> 1) & 3)))*8);
          acc[nt] = MFMA16x32(ap.s, bv.s, acc[nt]);
        }
      }
      __syncthreads();   // smem reads done before next tile's DMA
    }

    // ---- epilogue: normalize, o_lat -> LDS (A layout), o = o_lat @ wb_v^T ----
    float linv[4];
    #pragma unroll
    for (int i = 0; i < 4; ++i) linv[i] = 1.0f / li[i];
    const int pass = w >> 1;
    unsigned short* ola = smem + (w & 1) * 16 * 520;
    #pragma unroll 1
    for (int p = 0; p < 2; ++p) {
      if (pass == p) {
        #pragma unroll
        for (int nt = 0; nt < 32; ++nt) {
          #pragma unroll
          for (int i = 0; i < 4; ++i)
            ola[(quad*4+i)*520 + nt*16 + l16] = f2b(acc[nt][i] * linv[i]);
        }
      }
      __syncthreads();
      if (pass == p) {
        f32x4 oc[8];
        #pragma unroll
        for (int nt = 0; nt < 8; ++nt) oc[nt] = (f32x4){0.f,0.f,0.f,0.f};
        #pragma unroll
        for (int kc = 0; kc < 16; ++kc) {
          U8 a; a.u = *(const uint4*)(ola + l16*520 + kc*32 + quad*8);
          #pragma unroll
          for (int nt = 0; nt < 8; ++nt) {
            U8 bw; bw.u = *(const uint4*)((const unsigned short*)wbv +
                           (long)(h*128 + nt*16 + l16)*512 + kc*32 + quad*8);
            oc[nt] = MFMA16x32(a.s, bw.s, oc[nt]);
          }
        }
        #pragma unroll
        for (int nt = 0; nt < 8; ++nt) {
          #pragma unroll
          for (int i = 0; i < 4; ++i)
            ((unsigned short*)obuf)[((long)b*S_TOK + q0 + w*16 + quad*4 + i)*2048
                                    + h*128 + nt*16 + l16] = f2b(oc[nt][i]);
        }
      }
      __syncthreads();
    }
  }
}

// ---------------------------------------------------------------------------
extern "C" void kernel_launch(void* const* d_in, const int* in_sizes, int n_in,
                              void* d_out, int out_size, void* d_ws, size_t ws_size,
                              hipStream_t stream)
{
  const float* x     = (const float*)d_in[0];
  const float* wq    = (const float*)d_in[1];
  const float* wkv_a = (const float*)d_in[2];
  const float* kvnw  = (const float*)d_in[3];
  const float* wkv_b = (const float*)d_in[4];
  const float* wo    = (const float*)d_in[5];
  const float* cosb  = (const float*)d_in[6];
  const float* sinb  = (const float*)d_in[7];
  float* out = (float*)d_out;

  size_t off = 0;
  char* wsb = (char*)d_ws;
  bf16* xb    = (bf16*)(wsb + off); off += (size_t)NROWS * 2048 * 2;   // 16.8 MB
  bf16* wqb   = (bf16*)(wsb + off); off += (size_t)3072 * 2048 * 2;    // 12.6 MB
  bf16* wab   = (bf16*)(wsb + off); off += (size_t)576  * 2048 * 2;    //  2.4 MB
  bf16* wob   = (bf16*)(wsb + off); off += (size_t)2048 * 2048 * 2;    //  8.4 MB
  bf16* wbkT  = (bf16*)(wsb + off); off += (size_t)NH * 512 * 128 * 2; //  2.1 MB
  bf16* wbvb  = (bf16*)(wsb + off); off += (size_t)1048576 * 2;        //  2.1 MB
  bf16* qbuf  = (bf16*)(wsb + off); off += (size_t)NROWS * 3072 * 2;   // 25.2 MB
  bf16* kvbuf = (bf16*)(wsb + off); off += (size_t)NROWS * 576  * 2;   //  4.7 MB
  bf16* ckvb  = (bf16*)(wsb + off); off += (size_t)NROWS * 512  * 2;   //  4.2 MB
  bf16* kpeb  = (bf16*)(wsb + off); off += (size_t)NROWS * 64   * 2;   //  0.5 MB
  bf16* qpeb  = (bf16*)(wsb + off); off += (size_t)NROWS * 1024 * 2;   //  8.4 MB
  bf16* qlatb = (bf16*)(wsb + off); off += (size_t)NROWS * 8192 * 2;   // 67.1 MB
  bf16* ckvT  = (bf16*)(wsb + off); off += (size_t)NROWS * 512  * 2;   //  4.2 MB (tiled+swz)
  bf16* obuf  = (bf16*)(wsb + off); off += (size_t)NROWS * 2048 * 2;   // 16.8 MB

  dim3 blk(256);
  // input/weight conversions
  cvt_bf16<<<dim3(8388608/1024),  blk, 0, stream>>>(x,     xb,  8388608);
  cvt_bf16<<<dim3(6291456/1024),  blk, 0, stream>>>(wq,    wqb, 6291456);
  cvt_bf16<<<dim3(1179648/1024),  blk, 0, stream>>>(wkv_a, wab, 1179648);
  cvt_bf16<<<dim3(4194304/1024),  blk, 0, stream>>>(wo,    wob, 4194304);
  tr_wbk<<<dim3(2, 8, NH), blk, 0, stream>>>(wkv_b, wbkT);
  wbv_cvt<<<dim3(4096), blk, 0, stream>>>(wkv_b, wbvb);
  // q = x @ wq^T
  gemm_mfma<bf16><<<dim3(3072/64, NROWS/64, 1), blk, 0, stream>>>(
      xb, wqb, qbuf, 2048, 2048, 2048, 3072, 0, 0, 0);
  ropeq<<<dim3(8192), blk, 0, stream>>>(qbuf, cosb, sinb, qpeb);
  // kv = x @ wkv_a^T
  gemm_mfma<bf16><<<dim3(576/64, NROWS/64, 1), blk, 0, stream>>>(
      xb, wab, kvbuf, 2048, 2048, 2048, 576, 0, 0, 0);
  kvprep<<<dim3(NROWS), dim3(64), 0, stream>>>(kvbuf, kvnw, cosb, sinb, ckvb, kpeb);
  tr64<<<dim3(S_TOK/64, 512/64, 2), blk, 0, stream>>>(ckvb, ckvT);
  // q_lat[h] = q_nope[:,h] @ wbkT[h]^T
  gemm_mfma<bf16><<<dim3(512/64, NROWS/64, NH), blk, 0, stream>>>(
      qbuf, wbkT, qlatb, 128, 3072, 128, 8192,
      (long)QKD, (long)512*128, (long)512);
  // MFMA flash attention (+ fused o_lat @ wb_v^T)
  attn_mfma<<<dim3(512), blk, 0, stream>>>(qlatb, qpeb, ckvb, kpeb, ckvT, wbvb, obuf);
  // out = o @ wo^T (f32 out)
  gemm_mfma<float><<<dim3(2048/64, NROWS/64, 1), blk, 0, stream>>>(
      obuf, wob, out, 2048, 2048, 2048, 2048, 0, 0, 0);
}

// Round 4
// 1075.851 us; speedup vs baseline: 1.0269x; 1.0269x over previous
//
#include <hip/hip_runtime.h>
#include <hip/hip_bf16.h>

typedef __hip_bfloat16 bf16;
typedef __attribute__((ext_vector_type(8))) short short8;   // 8 bf16 = 4 VGPRs (MFMA A/B frag)
typedef __attribute__((ext_vector_type(4))) float f32x4;    // MFMA C/D frag

#define S_TOK   2048
#define NROWS   4096        // B*S
#define NH      16
#define QKD     192
#define NOPE_   128
#define ROPE_   64
#define VDIM_   128
#define RANK    512
#define SCALE_F 0.07216878364870323f   // 192^-0.5
#define NEG_BIG -3.0e38f
#define DEFER_THR 8.0f

__device__ __forceinline__ float bl(unsigned u){ union{unsigned i; float f;} t; t.i = u << 16; return t.f; }
__device__ __forceinline__ float bh(unsigned u){ union{unsigned i; float f;} t; t.i = u & 0xffff0000u; return t.f; }
__device__ __forceinline__ unsigned short f2b(float f){
  bf16 h = __float2bfloat16(f);
  return *reinterpret_cast<unsigned short*>(&h);
}
__device__ __forceinline__ void store4(bf16* p, float a, float b, float c, float d){
  ushort4 u; u.x=f2b(a); u.y=f2b(b); u.z=f2b(c); u.w=f2b(d);
  *(ushort4*)p = u;
}
union U8 { uint4 u; short8 s; };
#define MFMA16x32(a,b,c) __builtin_amdgcn_mfma_f32_16x16x32_bf16(a,b,c,0,0,0)

// async global -> LDS DMA, 16 B per lane; dest wave-uniform base + lane*16.
__device__ __forceinline__ void gload16(const unsigned short* g, unsigned short* l)
{
  __builtin_amdgcn_global_load_lds(
      (const __attribute__((address_space(1))) unsigned int*)g,
      (__attribute__((address_space(3))) unsigned int*)l,
      16, 0, 0);
}

// ---------------------------------------------------------------------------
// cvt_bf16: f32 -> bf16 elementwise (n multiple of 1024)
// ---------------------------------------------------------------------------
__global__ __launch_bounds__(256) void cvt_bf16(const float* __restrict__ src,
                                                bf16* __restrict__ dst, int n)
{
  int g = (blockIdx.x * 256 + threadIdx.x) * 4;
  if (g < n) {
    float4 v = *(const float4*)(src + g);
    store4(dst + g, v.x, v.y, v.z, v.w);
  }
}

// ---------------------------------------------------------------------------
// tr_wbk: wkv_b K-half (h, d<128, c) f32 -> wbkT (h, c, d) bf16.  grid (2,8,16)
// ---------------------------------------------------------------------------
__global__ __launch_bounds__(256) void tr_wbk(const float* __restrict__ wkvb,
                                              bf16* __restrict__ wbkT)
{
  const int d0 = blockIdx.x << 6, c0 = blockIdx.y << 6, h = blockIdx.z;
  const int tid = threadIdx.x;
  __shared__ float tile[64*65];
  #pragma unroll
  for (int j = 0; j < 16; ++j) {
    int idx = tid + j*256; int r = idx >> 6, c = idx & 63;   // r=d, c=c
    tile[r*65 + c] = wkvb[((long)(h*256 + d0 + r))*512 + c0 + c];
  }
  __syncthreads();
  #pragma unroll
  for (int j = 0; j < 16; ++j) {
    int idx = tid + j*256; int r = idx >> 6, cc = idx & 63;  // r=c, cc=d
    ((unsigned short*)wbkT)[(long)h*65536 + (long)(c0 + r)*128 + d0 + cc] = f2b(tile[cc*65 + r]);
  }
}

// ---------------------------------------------------------------------------
// wbv_cvt: wkv_b V-half (16 x 128 x 512 f32) -> bf16 (same orientation)
// ---------------------------------------------------------------------------
__global__ __launch_bounds__(256) void wbv_cvt(const float* __restrict__ wkvb,
                                               bf16* __restrict__ wbv)
{
  int g = blockIdx.x * 256 + threadIdx.x;       // 1,048,576
  int h = g >> 16, rem = g & 65535;
  ((unsigned short*)wbv)[g] = f2b(wkvb[((long)(h*256 + NOPE_))*512 + rem]);
}

// ---------------------------------------------------------------------------
// MFMA GEMM: C[M,N] = A[M,K] @ W[N,K]^T, bf16 A/W, TOUT out.
// ---------------------------------------------------------------------------
template<typename TOUT>
__global__ __launch_bounds__(256) void gemm_mfma(
    const bf16* __restrict__ A, const bf16* __restrict__ W, TOUT* __restrict__ C,
    int K, int lda, int ldw, int ldc, long azs, long wzs, long czs)
{
  A += (long)blockIdx.z * azs;
  W += (long)blockIdx.z * wzs;
  C += (long)blockIdx.z * czs;
  __shared__ __align__(16) unsigned short As[8*65*8];   // 8320 B
  __shared__ __align__(16) unsigned short Ws[8*65*8];
  const int tid = threadIdx.x;
  const int m0 = blockIdx.y << 6, n0 = blockIdx.x << 6;
  const int w = tid >> 6, lane = tid & 63;
  const int quad = lane >> 4, l16 = lane & 15;

  const int r0 = tid >> 3, c80 = tid & 7;
  const int r1 = (tid + 256) >> 3;

  f32x4 acc[4];
  #pragma unroll
  for (int i = 0; i < 4; ++i) acc[i] = (f32x4){0.f,0.f,0.f,0.f};

  for (int k0 = 0; k0 < K; k0 += 64) {
    uint4 a0 = *(const uint4*)(A + (long)(m0 + r0)*lda + k0 + c80*8);
    uint4 a1 = *(const uint4*)(A + (long)(m0 + r1)*lda + k0 + c80*8);
    uint4 w0 = *(const uint4*)(W + (long)(n0 + r0)*ldw + k0 + c80*8);
    uint4 w1 = *(const uint4*)(W + (long)(n0 + r1)*ldw + k0 + c80*8);
    __syncthreads();
    *(uint4*)(As + (c80*65 + r0)*8) = a0;
    *(uint4*)(As + (c80*65 + r1)*8) = a1;
    *(uint4*)(Ws + (c80*65 + r0)*8) = w0;
    *(uint4*)(Ws + (c80*65 + r1)*8) = w1;
    __syncthreads();
    #pragma unroll
    for (int kc = 0; kc < 2; ++kc) {
      const int kcq = kc*4 + quad;
      U8 af; af.u = *(const uint4*)(As + (kcq*65 + w*16 + l16)*8);
      #pragma unroll
      for (int nt = 0; nt < 4; ++nt) {
        U8 bf_; bf_.u = *(const uint4*)(Ws + (kcq*65 + nt*16 + l16)*8);
        acc[nt] = MFMA16x32(af.s, bf_.s, acc[nt]);
      }
    }
  }
  #pragma unroll
  for (int nt = 0; nt < 4; ++nt) {
    #pragma unroll
    for (int i = 0; i < 4; ++i) {
      long row = m0 + w*16 + quad*4 + i;
      TOUT v;
      if constexpr (sizeof(TOUT) == 2) v = __float2bfloat16(acc[nt][i]);
      else                             v = acc[nt][i];
      C[row*ldc + n0 + nt*16 + l16] = v;
    }
  }
}

// ---------------------------------------------------------------------------
// kvprep (bf16 in): RMSNorm first 512 -> ckv (bf16), RoPE last 64 -> kpe (bf16)
// ---------------------------------------------------------------------------
__global__ __launch_bounds__(64) void kvprep(
    const bf16* __restrict__ kvbuf, const float* __restrict__ wnorm,
    const float* __restrict__ cosb, const float* __restrict__ sinb,
    bf16* __restrict__ ckv, bf16* __restrict__ kpe)
{
  const int row = blockIdx.x;
  const int s = row & (S_TOK - 1);
  const int lane = threadIdx.x;
  const unsigned short* kr = (const unsigned short*)kvbuf + (long)row * 576;
  uint4 u = *(const uint4*)(kr + lane*8);
  float v[8] = { bl(u.x), bh(u.x), bl(u.y), bh(u.y), bl(u.z), bh(u.z), bl(u.w), bh(u.w) };
  float ss = 0.f;
  #pragma unroll
  for (int j = 0; j < 8; ++j) ss += v[j]*v[j];
  #pragma unroll
  for (int off = 32; off > 0; off >>= 1) ss += __shfl_down(ss, off);
  ss = __shfl(ss, 0);
  const float scl = rsqrtf(ss * (1.0f/512.0f) + 1e-6f);
  float4 w0 = *(const float4*)(wnorm + lane*8);
  float4 w1 = *(const float4*)(wnorm + lane*8 + 4);
  bf16* cd = ckv + (long)row*512 + lane*8;
  store4(cd,   v[0]*scl*w0.x, v[1]*scl*w0.y, v[2]*scl*w0.z, v[3]*scl*w0.w);
  store4(cd+4, v[4]*scl*w1.x, v[5]*scl*w1.y, v[6]*scl*w1.z, v[7]*scl*w1.w);
  if (lane < 32) {
    unsigned pe = *(const unsigned*)(kr + 512 + 2*lane);
    float xe = bl(pe), xo = bh(pe);
    float c = cosb[s*32 + lane], sn = sinb[s*32 + lane];
    ushort2 o; o.x = f2b(xe*c - xo*sn); o.y = f2b(xe*sn + xo*c);
    *(ushort2*)((unsigned short*)kpe + (long)row*64 + 2*lane) = o;
  }
}

// ---------------------------------------------------------------------------
// ropeq (bf16 in): RoPE q_pe slice of qbuf -> qpe (bf16, 4096 x 16*64)
// ---------------------------------------------------------------------------
__global__ __launch_bounds__(256) void ropeq(
    const bf16* __restrict__ qbuf, const float* __restrict__ cosb,
    const float* __restrict__ sinb, bf16* __restrict__ qpe)
{
  int gid = blockIdx.x * 256 + threadIdx.x;       // 4096*16*32
  int row = gid >> 9; int rem = gid & 511;
  int h = rem >> 5, i = rem & 31;
  int s = row & (S_TOK - 1);
  unsigned pp = *(const unsigned*)((const unsigned short*)qbuf + (long)row*3072 + h*QKD + NOPE_ + 2*i);
  float xe = bl(pp), xo = bh(pp);
  float c = cosb[s*32 + i], sn = sinb[s*32 + i];
  ushort2 u; u.x = f2b(xe*c - xo*sn); u.y = f2b(xe*sn + xo*c);
  *(ushort2*)((unsigned short*)qpe + (long)row*1024 + h*64 + 2*i) = u;
}

// ---------------------------------------------------------------------------
// tr64: ckv (b, t, c) -> ckvT TILED+SWIZZLED: granule (per b, per 32-tok pair)
//   g(pair, c, tg) = pair*2048 + c*4 + (tg ^ ((c>>1)&3)),  tg = (t&31)>>3,
// element byte within granule = (t&7)*2.  (unchanged from round 3 — verified)
// ---------------------------------------------------------------------------
__global__ __launch_bounds__(256) void tr64(const bf16* __restrict__ ckv,
                                            bf16* __restrict__ ckvT)
{
  const int t0 = blockIdx.x << 6, c0 = blockIdx.y << 6, b = blockIdx.z;
  const int tid = threadIdx.x;
  __shared__ unsigned short tile[64*65];
  const unsigned short* src = (const unsigned short*)ckv + (long)b*S_TOK*512;
  #pragma unroll
  for (int j = 0; j < 16; ++j) {
    int idx = tid + j*256; int r = idx >> 6, c = idx & 63;
    tile[r*65 + c] = src[(long)(t0+r)*512 + c0 + c];
  }
  __syncthreads();
  unsigned short* dst = (unsigned short*)ckvT + (long)b*512*S_TOK;
  #pragma unroll
  for (int j = 0; j < 16; ++j) {
    int idx = tid + j*256; int r = idx >> 6, t = idx & 63;   // r: c offset, t: token offset
    int tt = t0 + t;
    int c  = c0 + r;
    long g = (long)(tt >> 5)*2048 + (long)c*4 + (((tt & 31) >> 3) ^ ((c >> 1) & 3));
    dst[g*8 + (tt & 7)] = tile[t*65 + r];
  }
}

// ---------------------------------------------------------------------------
// MFMA flash attention v7 — double-buffered 16-token K tiles + per-pair V,
// plain __syncthreads only.  Every DMA is issued >= 1 compute phase before
// the barrier that drains it -> staging latency hidden.
//
// LDS granule arenas (granule = 16 B):
//   Kbuf[b][0,1152): ckv 16x512 at g=t*64+(c8^(t&7)) [0,1024) + kpe 16x64 at
//                    1024 + t*8 + (c8p^(t&7));  two buffers at 0 / 1152.
//   V [2304,4352):   per-pair 32x512 V^T, g = c*4 + (tg ^ ((c>>1)&3)) (r3).
// P_s: per-wave 16 rows x 40 cols; even tile writes cols 0-15, odd 16-31.
// ---------------------------------------------------------------------------
#define STAGE_K(BUF, TI) do {                                                  \
    unsigned short* bs_ = smem + (size_t)(BUF)*1152*8;                         \
    const long tb_ = (long)(TI) << 4;                                          \
    _Pragma("unroll")                                                          \
    for (int j_ = 0; j_ < 4; ++j_) {                                           \
      const int u_ = tid + j_*256;                                             \
      const int t_ = u_ >> 6, c8_ = (u_ & 63) ^ (t_ & 7);                      \
      gload16(ckv_b + (tb_ + t_)*512 + c8_*8, bs_ + (j_*256 + w*64)*8);        \
    }                                                                          \
    { const int u_ = (w & 1)*64 + lane;                                        \
      const int t_ = u_ >> 3, c8p_ = (u_ & 7) ^ (t_ & 7);                      \
      gload16(kpe_b + (tb_ + t_)*64 + c8p_*8, bs_ + (1024 + (w & 1)*64)*8); }  \
  } while (0)

#define STAGE_V(PI) do {                                                       \
    const unsigned short* vt_ = ckvT_b + (long)(PI) * 16384;                   \
    _Pragma("unroll")                                                          \
    for (int j_ = 0; j_ < 8; ++j_)                                             \
      gload16(vt_ + (long)(tid + j_*256)*8, smem + (2304 + j_*256 + w*64)*8);  \
  } while (0)

__global__ __launch_bounds__(256, 2) void attn_mfma(
    const bf16* __restrict__ qlat,   // (4096, 16*512)
    const bf16* __restrict__ qpe,    // (4096, 16*64)
    const bf16* __restrict__ ckv,    // (4096, 512)
    const bf16* __restrict__ kpe,    // (4096, 64)
    const bf16* __restrict__ ckvT,   // (B, 64 pairs, 512, 32) swizzled
    const bf16* __restrict__ wbv,    // (16, 128, 512)
    bf16* __restrict__ obuf)         // (4096, 2048) bf16
{
  // XCD-aware remap: xcd 0-3 -> b=0, 4-7 -> b=1 (each XCD L2 holds one batch)
  const int phys = blockIdx.x;
  const int b  = (phys & 7) >> 2;
  const int r_ = ((phys & 3) << 6) | (phys >> 3);   // [0,256)
  const int qp = r_ & 15;
  const int h  = r_ >> 4;
  const int tid = threadIdx.x;
  const int w = tid >> 6, lane = tid & 63;
  const int quad = lane >> 4, l16 = lane & 15;

  __shared__ __align__(16) unsigned short smem[4352 * 8];    // 69,632 B
  __shared__ __align__(16) unsigned short P_s[4 * 16 * 40];  //  5,120 B

  const unsigned short* ckv_b  = (const unsigned short*)ckv  + (long)b*S_TOK*512;
  const unsigned short* kpe_b  = (const unsigned short*)kpe  + (long)b*S_TOK*64;
  const unsigned short* ckvT_b = (const unsigned short*)ckvT + (long)b*512*S_TOK;
  unsigned short* Pw = P_s + w*640;

  #pragma unroll 1
  for (int half = 0; half < 2; ++half) {
    const int qt = half ? qp : (31 - qp);      // big q-tile first
    const int q0 = qt << 6;

    // ---- Q fragments: A[m=l16][k=quad*8+j], 18 K-chunks (512 lat + 64 pe)
    const long qrow = (long)b*S_TOK + q0 + w*16 + l16;
    short8 qf[18];
    {
      const unsigned short* qlp = (const unsigned short*)qlat + qrow*8192 + h*512 + quad*8;
      const unsigned short* qpp = (const unsigned short*)qpe  + qrow*1024 + h*64  + quad*8;
      #pragma unroll
      for (int kc = 0; kc < 16; ++kc) { U8 t; t.u = *(const uint4*)(qlp + kc*32); qf[kc] = t.s; }
      { U8 t; t.u = *(const uint4*)(qpp);      qf[16] = t.s; }
      { U8 t; t.u = *(const uint4*)(qpp + 32); qf[17] = t.s; }
    }

    f32x4 acc[32];
    #pragma unroll
    for (int i = 0; i < 32; ++i) acc[i] = (f32x4){0.f,0.f,0.f,0.f};
    float mi[4] = {NEG_BIG,NEG_BIG,NEG_BIG,NEG_BIG};
    float li[4] = {0.f,0.f,0.f,0.f};

    const int myqmax = q0 + w*16 + 15;
    const int nt16 = (q0 >> 4) + 4;            // 16-token tiles (always even)

    // ---- prologue: stage K tile 0 into buf 0 ----
    STAGE_K(0, 0);
    __builtin_amdgcn_sched_barrier(0);
    __syncthreads();

    #pragma unroll 1
    for (int t = 0; t < nt16; ++t) {
      const int cur = t & 1;
      const int t0  = t << 4;
      // ---- issue prefetches first (hidden under this tile's compute) ----
      if (t + 1 < nt16) STAGE_K(cur ^ 1, t + 1);
      if (!(t & 1))     STAGE_V(t >> 1);
      __builtin_amdgcn_sched_barrier(0);

      const bool active = (t0 <= myqmax);
      if (active) {
        const unsigned short* bs = smem + (size_t)cur*1152*8;
        // ---- QK: one 16x16 C-tile, two independent MFMA chains for ILP ----
        f32x4 sa = (f32x4){0.f,0.f,0.f,0.f}, sb = sa;
        #pragma unroll
        for (int kc = 0; kc < 18; kc += 2) {
          const int kcq0 = kc*4 + quad, kcq1 = (kc+1)*4 + quad;
          const int g0 = (kc < 16)
              ? l16*64 + (kcq0 ^ (l16 & 7))
              : 1024 + l16*8 + ((kcq0 & 7) ^ (l16 & 7));
          const int g1 = (kc+1 < 16)
              ? l16*64 + (kcq1 ^ (l16 & 7))
              : 1024 + l16*8 + ((kcq1 & 7) ^ (l16 & 7));
          U8 b0; b0.u = *(const uint4*)(bs + g0*8);
          U8 b1; b1.u = *(const uint4*)(bs + g1*8);
          sa = MFMA16x32(qf[kc],   b0.s, sa);
          sb = MFMA16x32(qf[kc+1], b1.s, sb);
        }
        // ---- online softmax (strip of 16 cols), defer-max ----
        float s0[4], tm[4];
        #pragma unroll
        for (int i = 0; i < 4; ++i) {
          int qg = q0 + w*16 + quad*4 + i;
          float sv = sa[i] + sb[i];
          s0[i] = (t0 + l16 <= qg) ? sv*SCALE_F : NEG_BIG;
          tm[i] = s0[i];
        }
        #pragma unroll
        for (int d = 1; d < 16; d <<= 1) {
          #pragma unroll
          for (int i = 0; i < 4; ++i) tm[i] = fmaxf(tm[i], __shfl_xor(tm[i], d));
        }
        bool small = (tm[0] - mi[0] <= DEFER_THR) && (tm[1] - mi[1] <= DEFER_THR)
                  && (tm[2] - mi[2] <= DEFER_THR) && (tm[3] - mi[3] <= DEFER_THR);
        if (!__all(small)) {
          float al[4];
          #pragma unroll
          for (int i = 0; i < 4; ++i) {
            float mx = fmaxf(mi[i], tm[i]);
            al[i] = __expf(mi[i] - mx);
            mi[i] = mx;
            li[i] *= al[i];
          }
          #pragma unroll
          for (int nt = 0; nt < 32; ++nt) {
            #pragma unroll
            for (int i = 0; i < 4; ++i) acc[nt][i] *= al[i];
          }
          if (t & 1) {   // odd tile: even-tile P (cols 0-15) is stale -> fix
            #pragma unroll
            for (int i = 0; i < 4; ++i) {
              int r = (quad*4+i)*40 + l16;
              Pw[r] = f2b(bl((unsigned)Pw[r]) * al[i]);
            }
          }
        }
        const int cb = (t & 1) << 4;
        float rs[4];
        #pragma unroll
        for (int i = 0; i < 4; ++i) {
          float p0 = __expf(s0[i] - mi[i]);
          rs[i] = p0;
          Pw[(quad*4+i)*40 + cb + l16] = f2b(p0);
        }
        #pragma unroll
        for (int d = 1; d < 16; d <<= 1) {
          #pragma unroll
          for (int i = 0; i < 4; ++i) rs[i] += __shfl_xor(rs[i], d);
        }
        #pragma unroll
        for (int i = 0; i < 4; ++i) li[i] += rs[i];
      }

      // ---- PV at the odd tile of each pair (K = 32 tokens) ----
      if (t & 1) {
        const bool pactive = (t0 - 16 <= myqmax);   // pair's even tile active
        if (pactive) {
          if (!active) {   // odd half fully masked: zero cols 16-31
            #pragma unroll
            for (int i = 0; i < 4; ++i) Pw[(quad*4+i)*40 + 16 + l16] = 0;
          }
          U8 ap; ap.u = *(const uint4*)(Pw + l16*40 + quad*8);
          #pragma unroll
          for (int nt = 0; nt < 32; ++nt) {
            const int c = nt*16 + l16;
            U8 bv; bv.u = *(const uint4*)(smem + (2304 + c*4 + (quad ^ ((c >> 1) & 3)))*8);
            acc[nt] = MFMA16x32(ap.s, bv.s, acc[nt]);
          }
        }
      }
      __syncthreads();   // drains prefetch DMA (aged a full compute phase)
    }

    // ---- epilogue: normalize, o_lat -> LDS (A layout), o = o_lat @ wb_v^T ----
    float linv[4];
    #pragma unroll
    for (int i = 0; i < 4; ++i) linv[i] = 1.0f / li[i];
    const int pass = w >> 1;
    unsigned short* ola = smem + (w & 1) * 16 * 520;
    #pragma unroll 1
    for (int p = 0; p < 2; ++p) {
      if (pass == p) {
        #pragma unroll
        for (int nt = 0; nt < 32; ++nt) {
          #pragma unroll
          for (int i = 0; i < 4; ++i)
            ola[(quad*4+i)*520 + nt*16 + l16] = f2b(acc[nt][i] * linv[i]);
        }
      }
      __syncthreads();
      if (pass == p) {
        f32x4 oc[8];
        #pragma unroll
        for (int nt = 0; nt < 8; ++nt) oc[nt] = (f32x4){0.f,0.f,0.f,0.f};
        #pragma unroll
        for (int kc = 0; kc < 16; ++kc) {
          U8 a; a.u = *(const uint4*)(ola + l16*520 + kc*32 + quad*8);
          #pragma unroll
          for (int nt = 0; nt < 8; ++nt) {
            U8 bw; bw.u = *(const uint4*)((const unsigned short*)wbv +
                           (long)(h*128 + nt*16 + l16)*512 + kc*32 + quad*8);
            oc[nt] = MFMA16x32(a.s, bw.s, oc[nt]);
          }
        }
        #pragma unroll
        for (int nt = 0; nt < 8; ++nt) {
          #pragma unroll
          for (int i = 0; i < 4; ++i)
            ((unsigned short*)obuf)[((long)b*S_TOK + q0 + w*16 + quad*4 + i)*2048
                                    + h*128 + nt*16 + l16] = f2b(oc[nt][i]);
        }
      }
      __syncthreads();
    }
  }
}

// ---------------------------------------------------------------------------
extern "C" void kernel_launch(void* const* d_in, const int* in_sizes, int n_in,
                              void* d_out, int out_size, void* d_ws, size_t ws_size,
                              hipStream_t stream)
{
  const float* x     = (const float*)d_in[0];
  const float* wq    = (const float*)d_in[1];
  const float* wkv_a = (const float*)d_in[2];
  const float* kvnw  = (const float*)d_in[3];
  const float* wkv_b = (const float*)d_in[4];
  const float* wo    = (const float*)d_in[5];
  const float* cosb  = (const float*)d_in[6];
  const float* sinb  = (const float*)d_in[7];
  float* out = (float*)d_out;

  size_t off = 0;
  char* wsb = (char*)d_ws;
  bf16* xb    = (bf16*)(wsb + off); off += (size_t)NROWS * 2048 * 2;   // 16.8 MB
  bf16* wqb   = (bf16*)(wsb + off); off += (size_t)3072 * 2048 * 2;    // 12.6 MB
  bf16* wab   = (bf16*)(wsb + off); off += (size_t)576  * 2048 * 2;    //  2.4 MB
  bf16* wob   = (bf16*)(wsb + off); off += (size_t)2048 * 2048 * 2;    //  8.4 MB
  bf16* wbkT  = (bf16*)(wsb + off); off += (size_t)NH * 512 * 128 * 2; //  2.1 MB
  bf16* wbvb  = (bf16*)(wsb + off); off += (size_t)1048576 * 2;        //  2.1 MB
  bf16* qbuf  = (bf16*)(wsb + off); off += (size_t)NROWS * 3072 * 2;   // 25.2 MB
  bf16* kvbuf = (bf16*)(wsb + off); off += (size_t)NROWS * 576  * 2;   //  4.7 MB
  bf16* ckvb  = (bf16*)(wsb + off); off += (size_t)NROWS * 512  * 2;   //  4.2 MB
  bf16* kpeb  = (bf16*)(wsb + off); off += (size_t)NROWS * 64   * 2;   //  0.5 MB
  bf16* qpeb  = (bf16*)(wsb + off); off += (size_t)NROWS * 1024 * 2;   //  8.4 MB
  bf16* qlatb = (bf16*)(wsb + off); off += (size_t)NROWS * 8192 * 2;   // 67.1 MB
  bf16* ckvT  = (bf16*)(wsb + off); off += (size_t)NROWS * 512  * 2;   //  4.2 MB (tiled+swz)
  bf16* obuf  = (bf16*)(wsb + off); off += (size_t)NROWS * 2048 * 2;   // 16.8 MB

  dim3 blk(256);
  // input/weight conversions
  cvt_bf16<<<dim3(8388608/1024),  blk, 0, stream>>>(x,     xb,  8388608);
  cvt_bf16<<<dim3(6291456/1024),  blk, 0, stream>>>(wq,    wqb, 6291456);
  cvt_bf16<<<dim3(1179648/1024),  blk, 0, stream>>>(wkv_a, wab, 1179648);
  cvt_bf16<<<dim3(4194304/1024),  blk, 0, stream>>>(wo,    wob, 4194304);
  tr_wbk<<<dim3(2, 8, NH), blk, 0, stream>>>(wkv_b, wbkT);
  wbv_cvt<<<dim3(4096), blk, 0, stream>>>(wkv_b, wbvb);
  // q = x @ wq^T
  gemm_mfma<bf16><<<dim3(3072/64, NROWS/64, 1), blk, 0, stream>>>(
      xb, wqb, qbuf, 2048, 2048, 2048, 3072, 0, 0, 0);
  ropeq<<<dim3(8192), blk, 0, stream>>>(qbuf, cosb, sinb, qpeb);
  // kv = x @ wkv_a^T
  gemm_mfma<bf16><<<dim3(576/64, NROWS/64, 1), blk, 0, stream>>>(
      xb, wab, kvbuf, 2048, 2048, 2048, 576, 0, 0, 0);
  kvprep<<<dim3(NROWS), dim3(64), 0, stream>>>(kvbuf, kvnw, cosb, sinb, ckvb, kpeb);
  tr64<<<dim3(S_TOK/64, 512/64, 2), blk, 0, stream>>>(ckvb, ckvT);
  // q_lat[h] = q_nope[:,h] @ wbkT[h]^T
  gemm_mfma<bf16><<<dim3(512/64, NROWS/64, NH), blk, 0, stream>>>(
      qbuf, wbkT, qlatb, 128, 3072, 128, 8192,
      (long)QKD, (long)512*128, (long)512);
  // MFMA flash attention (+ fused o_lat @ wb_v^T)
  attn_mfma<<<dim3(512), blk, 0, stream>>>(qlatb, qpeb, ckvb, kpeb, ckvT, wbvb, obuf);
  // out = o @ wo^T (f32 out)
  gemm_mfma<float><<<dim3(2048/64, NROWS/64, 1), blk, 0, stream>>>(
      obuf, wob, out, 2048, 2048, 2048, 2048, 0, 0, 0);
}

// Round 5
// 592.307 us; speedup vs baseline: 1.8652x; 1.8164x over previous
//
#include <hip/hip_runtime.h>
#include <hip/hip_bf16.h>

typedef __hip_bfloat16 bf16;
typedef __attribute__((ext_vector_type(8))) short short8;   // 8 bf16 = 4 VGPRs (MFMA A/B frag)
typedef __attribute__((ext_vector_type(4))) float f32x4;    // MFMA C/D frag

#define S_TOK   2048
#define NROWS   4096        // B*S
#define NH      16
#define QKD     192
#define NOPE_   128
#define ROPE_   64
#define VDIM_   128
#define RANK    512
#define SCALE_F 0.07216878364870323f   // 192^-0.5
#define NEG_BIG -3.0e38f
#define DEFER_THR 8.0f

__device__ __forceinline__ float bl(unsigned u){ union{unsigned i; float f;} t; t.i = u << 16; return t.f; }
__device__ __forceinline__ float bh(unsigned u){ union{unsigned i; float f;} t; t.i = u & 0xffff0000u; return t.f; }
__device__ __forceinline__ unsigned short f2b(float f){
  bf16 h = __float2bfloat16(f);
  return *reinterpret_cast<unsigned short*>(&h);
}
__device__ __forceinline__ void store4(bf16* p, float a, float b, float c, float d){
  ushort4 u; u.x=f2b(a); u.y=f2b(b); u.z=f2b(c); u.w=f2b(d);
  *(ushort4*)p = u;
}
union U8 { uint4 u; short8 s; };
#define MFMA16x32(a,b,c) __builtin_amdgcn_mfma_f32_16x16x32_bf16(a,b,c,0,0,0)

// async global -> LDS DMA, 16 B per lane; dest wave-uniform base + lane*16.
__device__ __forceinline__ void gload16(const unsigned short* g, unsigned short* l)
{
  __builtin_amdgcn_global_load_lds(
      (const __attribute__((address_space(1))) unsigned int*)g,
      (__attribute__((address_space(3))) unsigned int*)l,
      16, 0, 0);
}

// ---------------------------------------------------------------------------
// cvt_bf16: f32 -> bf16 elementwise (n multiple of 1024)
// ---------------------------------------------------------------------------
__global__ __launch_bounds__(256) void cvt_bf16(const float* __restrict__ src,
                                                bf16* __restrict__ dst, int n)
{
  int g = (blockIdx.x * 256 + threadIdx.x) * 4;
  if (g < n) {
    float4 v = *(const float4*)(src + g);
    store4(dst + g, v.x, v.y, v.z, v.w);
  }
}

// ---------------------------------------------------------------------------
// wbhalf_cvt: wkv_b half (h, rowoff+d<128 rows, c 512) f32 -> bf16 (h,128,512)
// ---------------------------------------------------------------------------
__global__ __launch_bounds__(256) void wbhalf_cvt(const float* __restrict__ wkvb,
                                                  bf16* __restrict__ dst, int rowoff)
{
  int g = blockIdx.x * 256 + threadIdx.x;       // 16*128*512 = 1,048,576
  int h = g >> 16, rem = g & 65535;
  int d = rem >> 9, c = rem & 511;
  ((unsigned short*)dst)[g] = f2b(wkvb[((long)(h*256 + rowoff + d))*512 + c]);
}

// ---------------------------------------------------------------------------
// MFMA GEMM: C[M,N] = A[M,K] @ W[N,K]^T, bf16 A/W, TOUT out.
// ---------------------------------------------------------------------------
template<typename TOUT>
__global__ __launch_bounds__(256) void gemm_mfma(
    const bf16* __restrict__ A, const bf16* __restrict__ W, TOUT* __restrict__ C,
    int K, int lda, int ldw, int ldc, long azs, long wzs, long czs)
{
  A += (long)blockIdx.z * azs;
  W += (long)blockIdx.z * wzs;
  C += (long)blockIdx.z * czs;
  __shared__ __align__(16) unsigned short As[8*65*8];   // 8320 B
  __shared__ __align__(16) unsigned short Ws[8*65*8];
  const int tid = threadIdx.x;
  const int m0 = blockIdx.y << 6, n0 = blockIdx.x << 6;
  const int w = tid >> 6, lane = tid & 63;
  const int quad = lane >> 4, l16 = lane & 15;

  const int r0 = tid >> 3, c80 = tid & 7;
  const int r1 = (tid + 256) >> 3;

  f32x4 acc[4];
  #pragma unroll
  for (int i = 0; i < 4; ++i) acc[i] = (f32x4){0.f,0.f,0.f,0.f};

  for (int k0 = 0; k0 < K; k0 += 64) {
    uint4 a0 = *(const uint4*)(A + (long)(m0 + r0)*lda + k0 + c80*8);
    uint4 a1 = *(const uint4*)(A + (long)(m0 + r1)*lda + k0 + c80*8);
    uint4 w0 = *(const uint4*)(W + (long)(n0 + r0)*ldw + k0 + c80*8);
    uint4 w1 = *(const uint4*)(W + (long)(n0 + r1)*ldw + k0 + c80*8);
    __syncthreads();
    *(uint4*)(As + (c80*65 + r0)*8) = a0;
    *(uint4*)(As + (c80*65 + r1)*8) = a1;
    *(uint4*)(Ws + (c80*65 + r0)*8) = w0;
    *(uint4*)(Ws + (c80*65 + r1)*8) = w1;
    __syncthreads();
    #pragma unroll
    for (int kc = 0; kc < 2; ++kc) {
      const int kcq = kc*4 + quad;
      U8 af; af.u = *(const uint4*)(As + (kcq*65 + w*16 + l16)*8);
      #pragma unroll
      for (int nt = 0; nt < 4; ++nt) {
        U8 bf_; bf_.u = *(const uint4*)(Ws + (kcq*65 + nt*16 + l16)*8);
        acc[nt] = MFMA16x32(af.s, bf_.s, acc[nt]);
      }
    }
  }
  #pragma unroll
  for (int nt = 0; nt < 4; ++nt) {
    #pragma unroll
    for (int i = 0; i < 4; ++i) {
      long row = m0 + w*16 + quad*4 + i;
      TOUT v;
      if constexpr (sizeof(TOUT) == 2) v = __float2bfloat16(acc[nt][i]);
      else                             v = acc[nt][i];
      C[row*ldc + n0 + nt*16 + l16] = v;
    }
  }
}

// ---------------------------------------------------------------------------
// kvprep (bf16 in): RMSNorm first 512 -> ckv (bf16), RoPE last 64 -> kpe (bf16)
// ---------------------------------------------------------------------------
__global__ __launch_bounds__(64) void kvprep(
    const bf16* __restrict__ kvbuf, const float* __restrict__ wnorm,
    const float* __restrict__ cosb, const float* __restrict__ sinb,
    bf16* __restrict__ ckv, bf16* __restrict__ kpe)
{
  const int row = blockIdx.x;
  const int s = row & (S_TOK - 1);
  const int lane = threadIdx.x;
  const unsigned short* kr = (const unsigned short*)kvbuf + (long)row * 576;
  uint4 u = *(const uint4*)(kr + lane*8);
  float v[8] = { bl(u.x), bh(u.x), bl(u.y), bh(u.y), bl(u.z), bh(u.z), bl(u.w), bh(u.w) };
  float ss = 0.f;
  #pragma unroll
  for (int j = 0; j < 8; ++j) ss += v[j]*v[j];
  #pragma unroll
  for (int off = 32; off > 0; off >>= 1) ss += __shfl_down(ss, off);
  ss = __shfl(ss, 0);
  const float scl = rsqrtf(ss * (1.0f/512.0f) + 1e-6f);
  float4 w0 = *(const float4*)(wnorm + lane*8);
  float4 w1 = *(const float4*)(wnorm + lane*8 + 4);
  bf16* cd = ckv + (long)row*512 + lane*8;
  store4(cd,   v[0]*scl*w0.x, v[1]*scl*w0.y, v[2]*scl*w0.z, v[3]*scl*w0.w);
  store4(cd+4, v[4]*scl*w1.x, v[5]*scl*w1.y, v[6]*scl*w1.z, v[7]*scl*w1.w);
  if (lane < 32) {
    unsigned pe = *(const unsigned*)(kr + 512 + 2*lane);
    float xe = bl(pe), xo = bh(pe);
    float c = cosb[s*32 + lane], sn = sinb[s*32 + lane];
    ushort2 o; o.x = f2b(xe*c - xo*sn); o.y = f2b(xe*sn + xo*c);
    *(ushort2*)((unsigned short*)kpe + (long)row*64 + 2*lane) = o;
  }
}

// ---------------------------------------------------------------------------
// kpe_bcast: kpe (4096,64) -> khbuf[row, h*192+128 .. +192) for all 16 heads
// ---------------------------------------------------------------------------
__global__ __launch_bounds__(256) void kpe_bcast(const bf16* __restrict__ kpe,
                                                 bf16* __restrict__ khbuf)
{
  int gid = blockIdx.x * 256 + threadIdx.x;    // 4096*16*32
  int row = gid >> 9; int rem = gid & 511;
  int h = rem >> 5, i = rem & 31;
  unsigned pe = *(const unsigned*)((const unsigned short*)kpe + (long)row*64 + 2*i);
  *(unsigned*)((unsigned short*)khbuf + (long)row*3072 + h*192 + 128 + 2*i) = pe;
}

// ---------------------------------------------------------------------------
// ropeq: RoPE q_pe slice of qbuf IN PLACE (per head, slots 128..192)
// ---------------------------------------------------------------------------
__global__ __launch_bounds__(256) void ropeq(
    bf16* __restrict__ qbuf, const float* __restrict__ cosb,
    const float* __restrict__ sinb)
{
  int gid = blockIdx.x * 256 + threadIdx.x;       // 4096*16*32
  int row = gid >> 9; int rem = gid & 511;
  int h = rem >> 5, i = rem & 31;
  int s = row & (S_TOK - 1);
  unsigned short* p = (unsigned short*)qbuf + (long)row*3072 + h*QKD + NOPE_ + 2*i;
  unsigned pp = *(const unsigned*)p;
  float xe = bl(pp), xo = bh(pp);
  float c = cosb[s*32 + i], sn = sinb[s*32 + i];
  ushort2 u; u.x = f2b(xe*c - xo*sn); u.y = f2b(xe*sn + xo*c);
  *(ushort2*)p = u;
}

// ---------------------------------------------------------------------------
// tr_v: vbuf (b*2048+t, h*128+d) -> vT per (b,h), 32-token tiles, swizzled:
//   granule g = (b*16+h)*32768 + (t>>5)*512 + d*4 + (((t&31)>>3)^((d>>1)&3)),
//   element byte (t&7)*2.  (same verified swizzle family as round-3 tr64)
// ---------------------------------------------------------------------------
__global__ __launch_bounds__(256) void tr_v(const bf16* __restrict__ vbuf,
                                            bf16* __restrict__ vT)
{
  const int t0 = blockIdx.x << 6, d0 = blockIdx.y << 6;
  const int b = blockIdx.z >> 4, h = blockIdx.z & 15;
  const int tid = threadIdx.x;
  __shared__ unsigned short tile[64*65];
  #pragma unroll
  for (int j = 0; j < 16; ++j) {
    int idx = tid + j*256; int r = idx >> 6, c = idx & 63;   // r=t, c=d
    tile[r*65 + c] = ((const unsigned short*)vbuf)[((long)(b*S_TOK + t0 + r))*2048 + h*128 + d0 + c];
  }
  __syncthreads();
  #pragma unroll
  for (int j = 0; j < 16; ++j) {
    int idx = tid + j*256; int r = idx >> 6, t = idx & 63;   // r: d offset, t: token offset
    int tt = t0 + t;
    int d  = d0 + r;
    long g = (long)(b*16 + h)*32768 + (long)(tt >> 5)*512 + d*4 + (((tt & 31) >> 3) ^ ((d >> 1) & 3));
    ((unsigned short*)vT)[g*8 + (tt & 7)] = tile[t*65 + r];
  }
}

// ---------------------------------------------------------------------------
// MFMA flash attention v8 — de-absorbed: per-head K (192) / V (128).
// grid = 1024 = (b, h, qt); one 64-row q-tile per block; 4 waves x 16 rows.
// r1-verified barrier structure (stage -> sync -> compute -> sync).
//
// LDS granule arenas (granule = 16 B):
//   K [0,768):   32 t x 24 c8, g = t*24 + swz(c8,t),
//                swz(c8,t) = c8<16 ? (c8&8)|((c8^t)&7) : 16+((c8^t)&7)
//                (involution; QK B-read bank group = (kcq^l16)&7 -> conflict-free)
//   V [768,1280): 128 d x 4 tg, g = 768 + d*4 + (tg^((d>>1)&3))  (r3-verified)
// ---------------------------------------------------------------------------
__global__ __launch_bounds__(256, 3) void attn_mfma(
    const bf16* __restrict__ qbuf,   // (4096, 16*192) rope applied in place
    const bf16* __restrict__ khbuf,  // (4096, 16*192) per-head K
    const bf16* __restrict__ vT,     // (B,16,64 tiles,512 granules) swizzled
    bf16* __restrict__ obuf)         // (4096, 2048) bf16
{
  // XCD-aware remap: xcd = phys&7; xcd 0-3 -> b=0, 4-7 -> b=1; bijective.
  const int phys = blockIdx.x;
  const int b  = (phys & 7) >> 2;
  const int r_ = ((phys & 3) << 7) | (phys >> 3);   // [0,512)
  const int h  = r_ >> 5;
  const int qt = r_ & 31;
  const int q0 = qt << 6;
  const int tid = threadIdx.x;
  const int w = tid >> 6, lane = tid & 63;
  const int quad = lane >> 4, l16 = lane & 15;

  __shared__ __align__(16) unsigned short smem[1280 * 8];    // 20,480 B
  __shared__ __align__(16) unsigned short P_s[4 * 16 * 40];  //  5,120 B

  const unsigned short* kh_b = (const unsigned short*)khbuf + (long)b*S_TOK*3072 + h*192;
  const unsigned short* vt_b = (const unsigned short*)vT + (long)(b*16 + h)*32768*8;
  unsigned short* Pw = P_s + w*640;

  // ---- Q fragments: 6 K-chunks of 32 (128 nope + 64 roped pe, contiguous)
  const long qrow = (long)b*S_TOK + q0 + w*16 + l16;
  short8 qf[6];
  {
    const unsigned short* qlp = (const unsigned short*)qbuf + qrow*3072 + h*192 + quad*8;
    #pragma unroll
    for (int kc = 0; kc < 6; ++kc) { U8 t; t.u = *(const uint4*)(qlp + kc*32); qf[kc] = t.s; }
  }

  f32x4 acc[8];
  #pragma unroll
  for (int i = 0; i < 8; ++i) acc[i] = (f32x4){0.f,0.f,0.f,0.f};
  float mi[4] = {NEG_BIG,NEG_BIG,NEG_BIG,NEG_BIG};
  float li[4] = {0.f,0.f,0.f,0.f};

  const int myqmax = q0 + w*16 + 15;
  const int ntiles = (q0 >> 5) + 2;

  #pragma unroll 1
  for (int tile = 0; tile < ntiles; ++tile) {
    const int t0 = tile << 5;
    // ---- stage K-tile (3 DMA) + V-tile (2 DMA), all coalesced 16B/lane ----
    #pragma unroll
    for (int j = 0; j < 3; ++j) {
      const int u = tid + j*256;
      const int t = u / 24, c8p = u - t*24;
      const int c8 = (c8p < 16) ? ((c8p & 8) | ((c8p ^ t) & 7))
                                : (16 + ((c8p ^ t) & 7));
      gload16(kh_b + (long)(t0 + t)*3072 + c8*8, smem + (j*256 + w*64)*8);
    }
    {
      const unsigned short* vt = vt_b + (long)tile * 512 * 8;
      #pragma unroll
      for (int j = 0; j < 2; ++j)
        gload16(vt + (long)(tid + j*256)*8, smem + (768 + j*256 + w*64)*8);
    }
    __syncthreads();   // drains vmcnt: DMA complete, previous reads done

    const bool active = (t0 <= myqmax);
    if (active) {
      // ---- scores: two 16x16 C-tiles (token halves), 6 kc each ----
      f32x4 sc0 = (f32x4){0.f,0.f,0.f,0.f}, sc1 = sc0;
      #pragma unroll
      for (int kc = 0; kc < 6; ++kc) {
        const int kcq = kc*4 + quad;
        const int sw = (kcq < 16) ? ((kcq & 8) | ((kcq ^ l16) & 7))
                                  : (16 + ((kcq ^ l16) & 7));   // (16+l16)&7==l16&7
        U8 b0; b0.u = *(const uint4*)(smem + (l16*24 + sw)*8);
        U8 b1; b1.u = *(const uint4*)(smem + ((16 + l16)*24 + sw)*8);
        sc0 = MFMA16x32(qf[kc], b0.s, sc0);
        sc1 = MFMA16x32(qf[kc], b1.s, sc1);
      }
      // ---- online softmax with defer-max ----
      float s0[4], s1[4], tm[4];
      #pragma unroll
      for (int i = 0; i < 4; ++i) {
        int qg = q0 + w*16 + quad*4 + i;
        s0[i] = (t0 + l16      <= qg) ? sc0[i]*SCALE_F : NEG_BIG;
        s1[i] = (t0 + 16 + l16 <= qg) ? sc1[i]*SCALE_F : NEG_BIG;
        tm[i] = fmaxf(s0[i], s1[i]);
      }
      #pragma unroll
      for (int d = 1; d < 16; d <<= 1) {
        #pragma unroll
        for (int i = 0; i < 4; ++i) tm[i] = fmaxf(tm[i], __shfl_xor(tm[i], d));
      }
      bool small = (tm[0] - mi[0] <= DEFER_THR) && (tm[1] - mi[1] <= DEFER_THR)
                && (tm[2] - mi[2] <= DEFER_THR) && (tm[3] - mi[3] <= DEFER_THR);
      if (!__all(small)) {
        float al[4];
        #pragma unroll
        for (int i = 0; i < 4; ++i) {
          float mx = fmaxf(mi[i], tm[i]);
          al[i] = __expf(mi[i] - mx);
          mi[i] = mx;
          li[i] *= al[i];
        }
        #pragma unroll
        for (int nt = 0; nt < 8; ++nt) {
          #pragma unroll
          for (int i = 0; i < 4; ++i) acc[nt][i] *= al[i];
        }
      }
      float rs[4];
      #pragma unroll
      for (int i = 0; i < 4; ++i) {
        float p0 = __expf(s0[i] - mi[i]);
        float p1 = __expf(s1[i] - mi[i]);
        rs[i] = p0 + p1;
        Pw[(quad*4+i)*40 + l16]      = f2b(p0);
        Pw[(quad*4+i)*40 + 16 + l16] = f2b(p1);
      }
      #pragma unroll
      for (int d = 1; d < 16; d <<= 1) {
        #pragma unroll
        for (int i = 0; i < 4; ++i) rs[i] += __shfl_xor(rs[i], d);
      }
      #pragma unroll
      for (int i = 0; i < 4; ++i) li[i] += rs[i];
      // ---- PV: A = P (LDS roundtrip), B = V^T tile (swizzled), 8 MFMA ----
      U8 ap; ap.u = *(const uint4*)(Pw + l16*40 + quad*8);
      #pragma unroll
      for (int nt = 0; nt < 8; ++nt) {
        const int c = nt*16 + l16;
        U8 bv; bv.u = *(const uint4*)(smem + (768 + c*4 + (quad ^ ((c >> 1) & 3)))*8);
        acc[nt] = MFMA16x32(ap.s, bv.s, acc[nt]);
      }
    }
    __syncthreads();   // smem reads done before next tile's DMA
  }

  // ---- epilogue: normalize, write O directly (no latent projection) ----
  float linv[4];
  #pragma unroll
  for (int i = 0; i < 4; ++i) linv[i] = 1.0f / li[i];
  #pragma unroll
  for (int nt = 0; nt < 8; ++nt) {
    #pragma unroll
    for (int i = 0; i < 4; ++i)
      ((unsigned short*)obuf)[((long)b*S_TOK + q0 + w*16 + quad*4 + i)*2048
                              + h*128 + nt*16 + l16] = f2b(acc[nt][i] * linv[i]);
  }
}

// ---------------------------------------------------------------------------
extern "C" void kernel_launch(void* const* d_in, const int* in_sizes, int n_in,
                              void* d_out, int out_size, void* d_ws, size_t ws_size,
                              hipStream_t stream)
{
  const float* x     = (const float*)d_in[0];
  const float* wq    = (const float*)d_in[1];
  const float* wkv_a = (const float*)d_in[2];
  const float* kvnw  = (const float*)d_in[3];
  const float* wkv_b = (const float*)d_in[4];
  const float* wo    = (const float*)d_in[5];
  const float* cosb  = (const float*)d_in[6];
  const float* sinb  = (const float*)d_in[7];
  float* out = (float*)d_out;

  size_t off = 0;
  char* wsb = (char*)d_ws;
  bf16* xb    = (bf16*)(wsb + off); off += (size_t)NROWS * 2048 * 2;   // 16.8 MB
  bf16* wqb   = (bf16*)(wsb + off); off += (size_t)3072 * 2048 * 2;    // 12.6 MB
  bf16* wab   = (bf16*)(wsb + off); off += (size_t)576  * 2048 * 2;    //  2.4 MB
  bf16* wob   = (bf16*)(wsb + off); off += (size_t)2048 * 2048 * 2;    //  8.4 MB
  bf16* wbkb  = (bf16*)(wsb + off); off += (size_t)1048576 * 2;        //  2.1 MB
  bf16* wbvb  = (bf16*)(wsb + off); off += (size_t)1048576 * 2;        //  2.1 MB
  bf16* qbuf  = (bf16*)(wsb + off); off += (size_t)NROWS * 3072 * 2;   // 25.2 MB
  bf16* kvbuf = (bf16*)(wsb + off); off += (size_t)NROWS * 576  * 2;   //  4.7 MB
  bf16* ckvb  = (bf16*)(wsb + off); off += (size_t)NROWS * 512  * 2;   //  4.2 MB
  bf16* kpeb  = (bf16*)(wsb + off); off += (size_t)NROWS * 64   * 2;   //  0.5 MB
  bf16* khbuf = (bf16*)(wsb + off); off += (size_t)NROWS * 3072 * 2;   // 25.2 MB
  bf16* vbuf  = (bf16*)(wsb + off); off += (size_t)NROWS * 2048 * 2;   // 16.8 MB
  bf16* vTb   = (bf16*)(wsb + off); off += (size_t)NROWS * 2048 * 2;   // 16.8 MB
  bf16* obuf  = (bf16*)(wsb + off); off += (size_t)NROWS * 2048 * 2;   // 16.8 MB

  dim3 blk(256);
  // input/weight conversions
  cvt_bf16<<<dim3(8388608/1024),  blk, 0, stream>>>(x,     xb,  8388608);
  cvt_bf16<<<dim3(6291456/1024),  blk, 0, stream>>>(wq,    wqb, 6291456);
  cvt_bf16<<<dim3(1179648/1024),  blk, 0, stream>>>(wkv_a, wab, 1179648);
  cvt_bf16<<<dim3(4194304/1024),  blk, 0, stream>>>(wo,    wob, 4194304);
  wbhalf_cvt<<<dim3(4096), blk, 0, stream>>>(wkv_b, wbkb, 0);      // K half
  wbhalf_cvt<<<dim3(4096), blk, 0, stream>>>(wkv_b, wbvb, NOPE_);  // V half
  // q = x @ wq^T, then RoPE q_pe slices in place
  gemm_mfma<bf16><<<dim3(3072/64, NROWS/64, 1), blk, 0, stream>>>(
      xb, wqb, qbuf, 2048, 2048, 2048, 3072, 0, 0, 0);
  ropeq<<<dim3(8192), blk, 0, stream>>>(qbuf, cosb, sinb);
  // kv = x @ wkv_a^T; rmsnorm + rope
  gemm_mfma<bf16><<<dim3(576/64, NROWS/64, 1), blk, 0, stream>>>(
      xb, wab, kvbuf, 2048, 2048, 2048, 576, 0, 0, 0);
  kvprep<<<dim3(NROWS), dim3(64), 0, stream>>>(kvbuf, kvnw, cosb, sinb, ckvb, kpeb);
  // de-absorbed per-head K/V:  K_h = ckv @ wbk[h]^T (+ kpe),  V_h = ckv @ wbv[h]^T
  kpe_bcast<<<dim3(8192), blk, 0, stream>>>(kpeb, khbuf);
  gemm_mfma<bf16><<<dim3(128/64, NROWS/64, NH), blk, 0, stream>>>(
      ckvb, wbkb, khbuf, 512, 512, 512, 3072, 0, (long)128*512, (long)192);
  gemm_mfma<bf16><<<dim3(128/64, NROWS/64, NH), blk, 0, stream>>>(
      ckvb, wbvb, vbuf, 512, 512, 512, 2048, 0, (long)128*512, (long)128);
  tr_v<<<dim3(S_TOK/64, 2, 32), blk, 0, stream>>>(vbuf, vTb);
  // standard MHA flash attention (192-dim QK, 128-dim PV)
  attn_mfma<<<dim3(1024), blk, 0, stream>>>(qbuf, khbuf, vTb, obuf);
  // out = o @ wo^T (f32 out)
  gemm_mfma<float><<<dim3(2048/64, NROWS/64, 1), blk, 0, stream>>>(
      obuf, wob, out, 2048, 2048, 2048, 2048, 0, 0, 0);
}

// Round 7
// 533.869 us; speedup vs baseline: 2.0694x; 1.1095x over previous
//
#include <hip/hip_runtime.h>
#include <hip/hip_bf16.h>

typedef __hip_bfloat16 bf16;
typedef __attribute__((ext_vector_type(8))) short short8;   // 8 bf16 = 4 VGPRs (MFMA A/B frag)
typedef __attribute__((ext_vector_type(4))) float f32x4;    // MFMA C/D frag

#define S_TOK   2048
#define NROWS   4096        // B*S
#define NH      16
#define QKD     192
#define NOPE_   128
#define ROPE_   64
#define VDIM_   128
#define RANK    512
#define SCALE_F 0.07216878364870323f   // 192^-0.5
#define NEG_BIG -3.0e38f
#define DEFER_THR 8.0f

__device__ __forceinline__ float bl(unsigned u){ union{unsigned i; float f;} t; t.i = u << 16; return t.f; }
__device__ __forceinline__ float bh(unsigned u){ union{unsigned i; float f;} t; t.i = u & 0xffff0000u; return t.f; }
__device__ __forceinline__ unsigned short f2b(float f){
  bf16 h = __float2bfloat16(f);
  return *reinterpret_cast<unsigned short*>(&h);
}
__device__ __forceinline__ void store4(bf16* p, float a, float b, float c, float d){
  ushort4 u; u.x=f2b(a); u.y=f2b(b); u.z=f2b(c); u.w=f2b(d);
  *(ushort4*)p = u;
}
union U8 { uint4 u; short8 s; };
#define MFMA16x32(a,b,c) __builtin_amdgcn_mfma_f32_16x16x32_bf16(a,b,c,0,0,0)

// async global -> LDS DMA, 16 B per lane; dest wave-uniform base + lane*16.
__device__ __forceinline__ void gload16(const unsigned short* g, unsigned short* l)
{
  __builtin_amdgcn_global_load_lds(
      (const __attribute__((address_space(1))) unsigned int*)g,
      (__attribute__((address_space(3))) unsigned int*)l,
      16, 0, 0);
}

// ---------------------------------------------------------------------------
// cvt_bf16: f32 -> bf16 elementwise (n multiple of 1024)
// ---------------------------------------------------------------------------
__global__ __launch_bounds__(256) void cvt_bf16(const float* __restrict__ src,
                                                bf16* __restrict__ dst, int n)
{
  int g = (blockIdx.x * 256 + threadIdx.x) * 4;
  if (g < n) {
    float4 v = *(const float4*)(src + g);
    store4(dst + g, v.x, v.y, v.z, v.w);
  }
}

// ---------------------------------------------------------------------------
// wbhalf_cvt: wkv_b half (h, rowoff+d<128 rows, c 512) f32 -> bf16 (h,128,512)
// ---------------------------------------------------------------------------
__global__ __launch_bounds__(256) void wbhalf_cvt(const float* __restrict__ wkvb,
                                                  bf16* __restrict__ dst, int rowoff)
{
  int g = blockIdx.x * 256 + threadIdx.x;       // 16*128*512 = 1,048,576
  int h = g >> 16, rem = g & 65535;
  int d = rem >> 9, c = rem & 511;
  ((unsigned short*)dst)[g] = f2b(wkvb[((long)(h*256 + rowoff + d))*512 + c]);
}

// ---------------------------------------------------------------------------
// MFMA GEMM 64^2 (legacy, for N not divisible by 128): C = A @ W^T
// ---------------------------------------------------------------------------
template<typename TOUT>
__global__ __launch_bounds__(256) void gemm_mfma(
    const bf16* __restrict__ A, const bf16* __restrict__ W, TOUT* __restrict__ C,
    int K, int lda, int ldw, int ldc, long azs, long wzs, long czs)
{
  A += (long)blockIdx.z * azs;
  W += (long)blockIdx.z * wzs;
  C += (long)blockIdx.z * czs;
  __shared__ __align__(16) unsigned short As[8*65*8];   // 8320 B
  __shared__ __align__(16) unsigned short Ws[8*65*8];
  const int tid = threadIdx.x;
  const int m0 = blockIdx.y << 6, n0 = blockIdx.x << 6;
  const int w = tid >> 6, lane = tid & 63;
  const int quad = lane >> 4, l16 = lane & 15;

  const int r0 = tid >> 3, c80 = tid & 7;
  const int r1 = (tid + 256) >> 3;

  f32x4 acc[4];
  #pragma unroll
  for (int i = 0; i < 4; ++i) acc[i] = (f32x4){0.f,0.f,0.f,0.f};

  for (int k0 = 0; k0 < K; k0 += 64) {
    uint4 a0 = *(const uint4*)(A + (long)(m0 + r0)*lda + k0 + c80*8);
    uint4 a1 = *(const uint4*)(A + (long)(m0 + r1)*lda + k0 + c80*8);
    uint4 w0 = *(const uint4*)(W + (long)(n0 + r0)*ldw + k0 + c80*8);
    uint4 w1 = *(const uint4*)(W + (long)(n0 + r1)*ldw + k0 + c80*8);
    __syncthreads();
    *(uint4*)(As + (c80*65 + r0)*8) = a0;
    *(uint4*)(As + (c80*65 + r1)*8) = a1;
    *(uint4*)(Ws + (c80*65 + r0)*8) = w0;
    *(uint4*)(Ws + (c80*65 + r1)*8) = w1;
    __syncthreads();
    #pragma unroll
    for (int kc = 0; kc < 2; ++kc) {
      const int kcq = kc*4 + quad;
      U8 af; af.u = *(const uint4*)(As + (kcq*65 + w*16 + l16)*8);
      #pragma unroll
      for (int nt = 0; nt < 4; ++nt) {
        U8 bf_; bf_.u = *(const uint4*)(Ws + (kcq*65 + nt*16 + l16)*8);
        acc[nt] = MFMA16x32(af.s, bf_.s, acc[nt]);
      }
    }
  }
  #pragma unroll
  for (int nt = 0; nt < 4; ++nt) {
    #pragma unroll
    for (int i = 0; i < 4; ++i) {
      long row = m0 + w*16 + quad*4 + i;
      TOUT v;
      if constexpr (sizeof(TOUT) == 2) v = __float2bfloat16(acc[nt][i]);
      else                             v = acc[nt][i];
      C[row*ldc + n0 + nt*16 + l16] = v;
    }
  }
}

// ---------------------------------------------------------------------------
// gemm128: m97-structure 128x128 tile, BK=64, global_load_lds staging,
// XOR-swizzled LDS (source-side; dest linear).  C[M,N] = A[M,K] @ W[N,K]^T.
// Grid (N/128, M/128, Z), 256 threads (4 waves, 2x2 wave quadrants, 4x4 acc).
// LDS granules: A tile [0,1024): g = row*8 + (c8 ^ (row&7)); W at [1024,2048).
// Frag reads: g%8 = kcq ^ (l16&7) -> 8 distinct 16B slots (conflict-free).
// ---------------------------------------------------------------------------
template<typename TOUT>
__global__ __launch_bounds__(256) void gemm128(
    const bf16* __restrict__ A, const bf16* __restrict__ W, TOUT* __restrict__ C,
    int K, int lda, int ldw, int ldc, long azs, long wzs, long czs)
{
  const unsigned short* Au = (const unsigned short*)A + (long)blockIdx.z * azs;
  const unsigned short* Wu = (const unsigned short*)W + (long)blockIdx.z * wzs;
  C += (long)blockIdx.z * czs;
  __shared__ __align__(16) unsigned short smem[2048 * 8];   // 32,768 B
  const int tid = threadIdx.x;
  const int m0 = blockIdx.y << 7, n0 = blockIdx.x << 7;
  const int w = tid >> 6, lane = tid & 63;
  const int quad = lane >> 4, l16 = lane & 15;
  const int wr = w >> 1, wc = w & 1;

  f32x4 acc[4][4];
  #pragma unroll
  for (int mt = 0; mt < 4; ++mt)
    #pragma unroll
    for (int nt = 0; nt < 4; ++nt) acc[mt][nt] = (f32x4){0.f,0.f,0.f,0.f};

  for (int k0 = 0; k0 < K; k0 += 64) {
    // ---- stage A (4 DMA) + W (4 DMA); dest linear, source XOR-swizzled ----
    #pragma unroll
    for (int j = 0; j < 4; ++j) {
      const int u = tid + j*256;
      const int row = u >> 3, c8 = (u & 7) ^ (row & 7);
      gload16(Au + (long)(m0 + row)*lda + k0 + c8*8, smem + (j*256 + w*64)*8);
    }
    #pragma unroll
    for (int j = 0; j < 4; ++j) {
      const int u = tid + j*256;
      const int row = u >> 3, c8 = (u & 7) ^ (row & 7);
      gload16(Wu + (long)(n0 + row)*ldw + k0 + c8*8, smem + (1024 + j*256 + w*64)*8);
    }
    __syncthreads();   // DMA landed; previous-iter reads done
    #pragma unroll
    for (int kc = 0; kc < 2; ++kc) {
      const int kcq = kc*4 + quad;
      U8 af[4];
      #pragma unroll
      for (int mt = 0; mt < 4; ++mt) {
        const int row = wr*64 + mt*16 + l16;
        af[mt].u = *(const uint4*)(smem + (row*8 + (kcq ^ (row & 7)))*8);
      }
      #pragma unroll
      for (int nt = 0; nt < 4; ++nt) {
        const int rowb = wc*64 + nt*16 + l16;
        U8 bf_; bf_.u = *(const uint4*)(smem + (1024 + rowb*8 + (kcq ^ (rowb & 7)))*8);
        #pragma unroll
        for (int mt = 0; mt < 4; ++mt)
          acc[mt][nt] = MFMA16x32(af[mt].s, bf_.s, acc[mt][nt]);
      }
    }
    __syncthreads();   // all reads done before next stage overwrites
  }
  #pragma unroll
  for (int mt = 0; mt < 4; ++mt) {
    #pragma unroll
    for (int nt = 0; nt < 4; ++nt) {
      #pragma unroll
      for (int i = 0; i < 4; ++i) {
        long row = m0 + wr*64 + mt*16 + quad*4 + i;
        int  col = n0 + wc*64 + nt*16 + l16;
        TOUT v;
        if constexpr (sizeof(TOUT) == 2) v = __float2bfloat16(acc[mt][nt][i]);
        else                             v = acc[mt][nt][i];
        C[row*ldc + col] = v;
      }
    }
  }
}

// ---------------------------------------------------------------------------
// kvprep (bf16 in): RMSNorm first 512 -> ckv (bf16), RoPE last 64 -> kpe (bf16)
// ---------------------------------------------------------------------------
__global__ __launch_bounds__(64) void kvprep(
    const bf16* __restrict__ kvbuf, const float* __restrict__ wnorm,
    const float* __restrict__ cosb, const float* __restrict__ sinb,
    bf16* __restrict__ ckv, bf16* __restrict__ kpe)
{
  const int row = blockIdx.x;
  const int s = row & (S_TOK - 1);
  const int lane = threadIdx.x;
  const unsigned short* kr = (const unsigned short*)kvbuf + (long)row * 576;
  uint4 u = *(const uint4*)(kr + lane*8);
  float v[8] = { bl(u.x), bh(u.x), bl(u.y), bh(u.y), bl(u.z), bh(u.z), bl(u.w), bh(u.w) };
  float ss = 0.f;
  #pragma unroll
  for (int j = 0; j < 8; ++j) ss += v[j]*v[j];
  #pragma unroll
  for (int off = 32; off > 0; off >>= 1) ss += __shfl_down(ss, off);
  ss = __shfl(ss, 0);
  const float scl = rsqrtf(ss * (1.0f/512.0f) + 1e-6f);
  float4 w0 = *(const float4*)(wnorm + lane*8);
  float4 w1 = *(const float4*)(wnorm + lane*8 + 4);
  bf16* cd = ckv + (long)row*512 + lane*8;
  store4(cd,   v[0]*scl*w0.x, v[1]*scl*w0.y, v[2]*scl*w0.z, v[3]*scl*w0.w);
  store4(cd+4, v[4]*scl*w1.x, v[5]*scl*w1.y, v[6]*scl*w1.z, v[7]*scl*w1.w);
  if (lane < 32) {
    unsigned pe = *(const unsigned*)(kr + 512 + 2*lane);
    float xe = bl(pe), xo = bh(pe);
    float c = cosb[s*32 + lane], sn = sinb[s*32 + lane];
    ushort2 o; o.x = f2b(xe*c - xo*sn); o.y = f2b(xe*sn + xo*c);
    *(ushort2*)((unsigned short*)kpe + (long)row*64 + 2*lane) = o;
  }
}

// ---------------------------------------------------------------------------
// kpe_bcast: kpe (4096,64) -> khbuf[row, h*192+128 .. +192) for all 16 heads
// ---------------------------------------------------------------------------
__global__ __launch_bounds__(256) void kpe_bcast(const bf16* __restrict__ kpe,
                                                 bf16* __restrict__ khbuf)
{
  int gid = blockIdx.x * 256 + threadIdx.x;    // 4096*16*32
  int row = gid >> 9; int rem = gid & 511;
  int h = rem >> 5, i = rem & 31;
  unsigned pe = *(const unsigned*)((const unsigned short*)kpe + (long)row*64 + 2*i);
  *(unsigned*)((unsigned short*)khbuf + (long)row*3072 + h*192 + 128 + 2*i) = pe;
}

// ---------------------------------------------------------------------------
// ropeq: RoPE q_pe slice of qbuf IN PLACE (per head, slots 128..192)
// ---------------------------------------------------------------------------
__global__ __launch_bounds__(256) void ropeq(
    bf16* __restrict__ qbuf, const float* __restrict__ cosb,
    const float* __restrict__ sinb)
{
  int gid = blockIdx.x * 256 + threadIdx.x;       // 4096*16*32
  int row = gid >> 9; int rem = gid & 511;
  int h = rem >> 5, i = rem & 31;
  int s = row & (S_TOK - 1);
  unsigned short* p = (unsigned short*)qbuf + (long)row*3072 + h*QKD + NOPE_ + 2*i;
  unsigned pp = *(const unsigned*)p;
  float xe = bl(pp), xo = bh(pp);
  float c = cosb[s*32 + i], sn = sinb[s*32 + i];
  ushort2 u; u.x = f2b(xe*c - xo*sn); u.y = f2b(xe*sn + xo*c);
  *(ushort2*)p = u;
}

// ---------------------------------------------------------------------------
// tr_v: vbuf (b*2048+t, h*128+d) -> vT per (b,h), 32-token tiles, swizzled:
//   granule g = (b*16+h)*32768 + (t>>5)*512 + d*4 + (((t&31)>>3)^((d>>1)&3)),
//   element byte (t&7)*2.
// ---------------------------------------------------------------------------
__global__ __launch_bounds__(256) void tr_v(const bf16* __restrict__ vbuf,
                                            bf16* __restrict__ vT)
{
  const int t0 = blockIdx.x << 6, d0 = blockIdx.y << 6;
  const int b = blockIdx.z >> 4, h = blockIdx.z & 15;
  const int tid = threadIdx.x;
  __shared__ unsigned short tile[64*65];
  #pragma unroll
  for (int j = 0; j < 16; ++j) {
    int idx = tid + j*256; int r = idx >> 6, c = idx & 63;   // r=t, c=d
    tile[r*65 + c] = ((const unsigned short*)vbuf)[((long)(b*S_TOK + t0 + r))*2048 + h*128 + d0 + c];
  }
  __syncthreads();
  #pragma unroll
  for (int j = 0; j < 16; ++j) {
    int idx = tid + j*256; int r = idx >> 6, t = idx & 63;   // r: d offset, t: token offset
    int tt = t0 + t;
    int d  = d0 + r;
    long g = (long)(b*16 + h)*32768 + (long)(tt >> 5)*512 + d*4 + (((tt & 31) >> 3) ^ ((d >> 1) & 3));
    ((unsigned short*)vT)[g*8 + (tt & 7)] = tile[t*65 + r];
  }
}

// ---------------------------------------------------------------------------
// MFMA flash attention v9 — de-absorbed per-head K (192) / V (128); v8
// verified structure; qt REVERSED so longest blocks dispatch first (LPT).
// ---------------------------------------------------------------------------
__global__ __launch_bounds__(256, 3) void attn_mfma(
    const bf16* __restrict__ qbuf,   // (4096, 16*192) rope applied in place
    const bf16* __restrict__ khbuf,  // (4096, 16*192) per-head K
    const bf16* __restrict__ vT,     // (B,16,64 tiles,512 granules) swizzled
    bf16* __restrict__ obuf)         // (4096, 2048) bf16
{
  // XCD-aware remap: xcd = phys&7; xcd 0-3 -> b=0, 4-7 -> b=1; bijective.
  const int phys = blockIdx.x;
  const int b  = (phys & 7) >> 2;
  const int r_ = ((phys & 3) << 7) | (phys >> 3);   // [0,512)
  const int h  = r_ >> 5;
  const int qt = 31 - (r_ & 31);                    // big q-tiles first
  const int q0 = qt << 6;
  const int tid = threadIdx.x;
  const int w = tid >> 6, lane = tid & 63;
  const int quad = lane >> 4, l16 = lane & 15;

  __shared__ __align__(16) unsigned short smem[1280 * 8];    // 20,480 B
  __shared__ __align__(16) unsigned short P_s[4 * 16 * 40];  //  5,120 B

  const unsigned short* kh_b = (const unsigned short*)khbuf + (long)b*S_TOK*3072 + h*192;
  const unsigned short* vt_b = (const unsigned short*)vT + (long)(b*16 + h)*32768*8;
  unsigned short* Pw = P_s + w*640;

  // ---- Q fragments: 6 K-chunks of 32 (128 nope + 64 roped pe, contiguous)
  const long qrow = (long)b*S_TOK + q0 + w*16 + l16;
  short8 qf[6];
  {
    const unsigned short* qlp = (const unsigned short*)qbuf + qrow*3072 + h*192 + quad*8;
    #pragma unroll
    for (int kc = 0; kc < 6; ++kc) { U8 t; t.u = *(const uint4*)(qlp + kc*32); qf[kc] = t.s; }
  }

  f32x4 acc[8];
  #pragma unroll
  for (int i = 0; i < 8; ++i) acc[i] = (f32x4){0.f,0.f,0.f,0.f};
  float mi[4] = {NEG_BIG,NEG_BIG,NEG_BIG,NEG_BIG};
  float li[4] = {0.f,0.f,0.f,0.f};

  const int myqmax = q0 + w*16 + 15;
  const int ntiles = (q0 >> 5) + 2;

  #pragma unroll 1
  for (int tile = 0; tile < ntiles; ++tile) {
    const int t0 = tile << 5;
    // ---- stage K-tile (3 DMA) + V-tile (2 DMA), all coalesced 16B/lane ----
    #pragma unroll
    for (int j = 0; j < 3; ++j) {
      const int u = tid + j*256;
      const int t = u / 24, c8p = u - t*24;
      const int c8 = (c8p < 16) ? ((c8p & 8) | ((c8p ^ t) & 7))
                                : (16 + ((c8p ^ t) & 7));
      gload16(kh_b + (long)(t0 + t)*3072 + c8*8, smem + (j*256 + w*64)*8);
    }
    {
      const unsigned short* vt = vt_b + (long)tile * 512 * 8;
      #pragma unroll
      for (int j = 0; j < 2; ++j)
        gload16(vt + (long)(tid + j*256)*8, smem + (768 + j*256 + w*64)*8);
    }
    __syncthreads();   // drains vmcnt: DMA complete, previous reads done

    const bool active = (t0 <= myqmax);
    if (active) {
      // ---- scores: two 16x16 C-tiles (token halves), 6 kc each ----
      f32x4 sc0 = (f32x4){0.f,0.f,0.f,0.f}, sc1 = sc0;
      #pragma unroll
      for (int kc = 0; kc < 6; ++kc) {
        const int kcq = kc*4 + quad;
        const int sw = (kcq < 16) ? ((kcq & 8) | ((kcq ^ l16) & 7))
                                  : (16 + ((kcq ^ l16) & 7));
        U8 b0; b0.u = *(const uint4*)(smem + (l16*24 + sw)*8);
        U8 b1; b1.u = *(const uint4*)(smem + ((16 + l16)*24 + sw)*8);
        sc0 = MFMA16x32(qf[kc], b0.s, sc0);
        sc1 = MFMA16x32(qf[kc], b1.s, sc1);
      }
      // ---- online softmax with defer-max ----
      float s0[4], s1[4], tm[4];
      #pragma unroll
      for (int i = 0; i < 4; ++i) {
        int qg = q0 + w*16 + quad*4 + i;
        s0[i] = (t0 + l16      <= qg) ? sc0[i]*SCALE_F : NEG_BIG;
        s1[i] = (t0 + 16 + l16 <= qg) ? sc1[i]*SCALE_F : NEG_BIG;
        tm[i] = fmaxf(s0[i], s1[i]);
      }
      #pragma unroll
      for (int d = 1; d < 16; d <<= 1) {
        #pragma unroll
        for (int i = 0; i < 4; ++i) tm[i] = fmaxf(tm[i], __shfl_xor(tm[i], d));
      }
      bool small = (tm[0] - mi[0] <= DEFER_THR) && (tm[1] - mi[1] <= DEFER_THR)
                && (tm[2] - mi[2] <= DEFER_THR) && (tm[3] - mi[3] <= DEFER_THR);
      if (!__all(small)) {
        float al[4];
        #pragma unroll
        for (int i = 0; i < 4; ++i) {
          float mx = fmaxf(mi[i], tm[i]);
          al[i] = __expf(mi[i] - mx);
          mi[i] = mx;
          li[i] *= al[i];
        }
        #pragma unroll
        for (int nt = 0; nt < 8; ++nt) {
          #pragma unroll
          for (int i = 0; i < 4; ++i) acc[nt][i] *= al[i];
        }
      }
      float rs[4];
      #pragma unroll
      for (int i = 0; i < 4; ++i) {
        float p0 = __expf(s0[i] - mi[i]);
        float p1 = __expf(s1[i] - mi[i]);
        rs[i] = p0 + p1;
        Pw[(quad*4+i)*40 + l16]      = f2b(p0);
        Pw[(quad*4+i)*40 + 16 + l16] = f2b(p1);
      }
      #pragma unroll
      for (int d = 1; d < 16; d <<= 1) {
        #pragma unroll
        for (int i = 0; i < 4; ++i) rs[i] += __shfl_xor(rs[i], d);
      }
      #pragma unroll
      for (int i = 0; i < 4; ++i) li[i] += rs[i];
      // ---- PV: A = P (LDS roundtrip), B = V^T tile (swizzled), 8 MFMA ----
      U8 ap; ap.u = *(const uint4*)(Pw + l16*40 + quad*8);
      #pragma unroll
      for (int nt = 0; nt < 8; ++nt) {
        const int c = nt*16 + l16;
        U8 bv; bv.u = *(const uint4*)(smem + (768 + c*4 + (quad ^ ((c >> 1) & 3)))*8);
        acc[nt] = MFMA16x32(ap.s, bv.s, acc[nt]);
      }
    }
    __syncthreads();   // smem reads done before next tile's DMA
  }

  // ---- epilogue: normalize, write O directly (no latent projection) ----
  float linv[4];
  #pragma unroll
  for (int i = 0; i < 4; ++i) linv[i] = 1.0f / li[i];
  #pragma unroll
  for (int nt = 0; nt < 8; ++nt) {
    #pragma unroll
    for (int i = 0; i < 4; ++i)
      ((unsigned short*)obuf)[((long)b*S_TOK + q0 + w*16 + quad*4 + i)*2048
                              + h*128 + nt*16 + l16] = f2b(acc[nt][i] * linv[i]);
  }
}

// ---------------------------------------------------------------------------
extern "C" void kernel_launch(void* const* d_in, const int* in_sizes, int n_in,
                              void* d_out, int out_size, void* d_ws, size_t ws_size,
                              hipStream_t stream)
{
  const float* x     = (const float*)d_in[0];
  const float* wq    = (const float*)d_in[1];
  const float* wkv_a = (const float*)d_in[2];
  const float* kvnw  = (const float*)d_in[3];
  const float* wkv_b = (const float*)d_in[4];
  const float* wo    = (const float*)d_in[5];
  const float* cosb  = (const float*)d_in[6];
  const float* sinb  = (const float*)d_in[7];
  float* out = (float*)d_out;

  size_t off = 0;
  char* wsb = (char*)d_ws;
  bf16* xb    = (bf16*)(wsb + off); off += (size_t)NROWS * 2048 * 2;   // 16.8 MB
  bf16* wqb   = (bf16*)(wsb + off); off += (size_t)3072 * 2048 * 2;    // 12.6 MB
  bf16* wab   = (bf16*)(wsb + off); off += (size_t)576  * 2048 * 2;    //  2.4 MB
  bf16* wob   = (bf16*)(wsb + off); off += (size_t)2048 * 2048 * 2;    //  8.4 MB
  bf16* wbkb  = (bf16*)(wsb + off); off += (size_t)1048576 * 2;        //  2.1 MB
  bf16* wbvb  = (bf16*)(wsb + off); off += (size_t)1048576 * 2;        //  2.1 MB
  bf16* qbuf  = (bf16*)(wsb + off); off += (size_t)NROWS * 3072 * 2;   // 25.2 MB
  bf16* kvbuf = (bf16*)(wsb + off); off += (size_t)NROWS * 576  * 2;   //  4.7 MB
  bf16* ckvb  = (bf16*)(wsb + off); off += (size_t)NROWS * 512  * 2;   //  4.2 MB
  bf16* kpeb  = (bf16*)(wsb + off); off += (size_t)NROWS * 64   * 2;   //  0.5 MB
  bf16* khbuf = (bf16*)(wsb + off); off += (size_t)NROWS * 3072 * 2;   // 25.2 MB
  bf16* vbuf  = (bf16*)(wsb + off); off += (size_t)NROWS * 2048 * 2;   // 16.8 MB
  bf16* vTb   = (bf16*)(wsb + off); off += (size_t)NROWS * 2048 * 2;   // 16.8 MB
  bf16* obuf  = (bf16*)(wsb + off); off += (size_t)NROWS * 2048 * 2;   // 16.8 MB

  dim3 blk(256);
  // input/weight conversions
  cvt_bf16<<<dim3(8388608/1024),  blk, 0, stream>>>(x,     xb,  8388608);
  cvt_bf16<<<dim3(6291456/1024),  blk, 0, stream>>>(wq,    wqb, 6291456);
  cvt_bf16<<<dim3(1179648/1024),  blk, 0, stream>>>(wkv_a, wab, 1179648);
  cvt_bf16<<<dim3(4194304/1024),  blk, 0, stream>>>(wo,    wob, 4194304);
  wbhalf_cvt<<<dim3(4096), blk, 0, stream>>>(wkv_b, wbkb, 0);      // K half
  wbhalf_cvt<<<dim3(4096), blk, 0, stream>>>(wkv_b, wbvb, NOPE_);  // V half
  // q = x @ wq^T (128-tile), then RoPE q_pe slices in place
  gemm128<bf16><<<dim3(3072/128, NROWS/128, 1), blk, 0, stream>>>(
      xb, wqb, qbuf, 2048, 2048, 2048, 3072, 0, 0, 0);
  ropeq<<<dim3(8192), blk, 0, stream>>>(qbuf, cosb, sinb);
  // kv = x @ wkv_a^T (N=576 -> legacy 64-tile); rmsnorm + rope
  gemm_mfma<bf16><<<dim3(576/64, NROWS/64, 1), blk, 0, stream>>>(
      xb, wab, kvbuf, 2048, 2048, 2048, 576, 0, 0, 0);
  kvprep<<<dim3(NROWS), dim3(64), 0, stream>>>(kvbuf, kvnw, cosb, sinb, ckvb, kpeb);
  // de-absorbed per-head K/V:  K_h = ckv @ wbk[h]^T (+ kpe),  V_h = ckv @ wbv[h]^T
  kpe_bcast<<<dim3(8192), blk, 0, stream>>>(kpeb, khbuf);
  gemm128<bf16><<<dim3(1, NROWS/128, NH), blk, 0, stream>>>(
      ckvb, wbkb, khbuf, 512, 512, 512, 3072, 0, (long)128*512, (long)192);
  gemm128<bf16><<<dim3(1, NROWS/128, NH), blk, 0, stream>>>(
      ckvb, wbvb, vbuf, 512, 512, 512, 2048, 0, (long)128*512, (long)128);
  tr_v<<<dim3(S_TOK/64, 2, 32), blk, 0, stream>>>(vbuf, vTb);
  // standard MHA flash attention (192-dim QK, 128-dim PV)
  attn_mfma<<<dim3(1024), blk, 0, stream>>>(qbuf, khbuf, vTb, obuf);
  // out = o @ wo^T (128-tile, f32 out)
  gemm128<float><<<dim3(2048/128, NROWS/128, 1), blk, 0, stream>>>(
      obuf, wob, out, 2048, 2048, 2048, 2048, 0, 0, 0);
}

// Round 8
// 456.503 us; speedup vs baseline: 2.4201x; 1.1695x over previous
//
#include <hip/hip_runtime.h>
#include <hip/hip_bf16.h>

typedef __hip_bfloat16 bf16;
typedef __attribute__((ext_vector_type(8))) short short8;   // 8 bf16 = 4 VGPRs (MFMA A/B frag)
typedef __attribute__((ext_vector_type(4))) float f32x4;    // MFMA C/D frag

#define S_TOK   2048
#define NROWS   4096        // B*S
#define NH      16
#define QKD     192
#define NOPE_   128
#define ROPE_   64
#define VDIM_   128
#define RANK    512
#define SCALE_F 0.07216878364870323f   // 192^-0.5
#define NEG_BIG -3.0e38f
#define DEFER_THR 8.0f

__device__ __forceinline__ float bl(unsigned u){ union{unsigned i; float f;} t; t.i = u << 16; return t.f; }
__device__ __forceinline__ float bh(unsigned u){ union{unsigned i; float f;} t; t.i = u & 0xffff0000u; return t.f; }
__device__ __forceinline__ unsigned short f2b(float f){
  bf16 h = __float2bfloat16(f);
  return *reinterpret_cast<unsigned short*>(&h);
}
__device__ __forceinline__ void store4(bf16* p, float a, float b, float c, float d){
  ushort4 u; u.x=f2b(a); u.y=f2b(b); u.z=f2b(c); u.w=f2b(d);
  *(ushort4*)p = u;
}
union U8 { uint4 u; short8 s; };
#define MFMA16x32(a,b,c) __builtin_amdgcn_mfma_f32_16x16x32_bf16(a,b,c,0,0,0)

// async global -> LDS DMA, 16 B per lane; dest wave-uniform base + lane*16.
__device__ __forceinline__ void gload16(const unsigned short* g, unsigned short* l)
{
  __builtin_amdgcn_global_load_lds(
      (const __attribute__((address_space(1))) unsigned int*)g,
      (__attribute__((address_space(3))) unsigned int*)l,
      16, 0, 0);
}

// ---------------------------------------------------------------------------
// cvt_bf16: f32 -> bf16 elementwise (n multiple of 1024)
// ---------------------------------------------------------------------------
__global__ __launch_bounds__(256) void cvt_bf16(const float* __restrict__ src,
                                                bf16* __restrict__ dst, int n)
{
  int g = (blockIdx.x * 256 + threadIdx.x) * 4;
  if (g < n) {
    float4 v = *(const float4*)(src + g);
    store4(dst + g, v.x, v.y, v.z, v.w);
  }
}

// ---------------------------------------------------------------------------
// wbhalf_cvt: wkv_b half (h, rowoff+d<128 rows, c 512) f32 -> bf16 (h,128,512)
// ---------------------------------------------------------------------------
__global__ __launch_bounds__(256) void wbhalf_cvt(const float* __restrict__ wkvb,
                                                  bf16* __restrict__ dst, int rowoff)
{
  int g = blockIdx.x * 256 + threadIdx.x;       // 16*128*512 = 1,048,576
  int h = g >> 16, rem = g & 65535;
  int d = rem >> 9, c = rem & 511;
  ((unsigned short*)dst)[g] = f2b(wkvb[((long)(h*256 + rowoff + d))*512 + c]);
}

// ---------------------------------------------------------------------------
// MFMA GEMM 64^2 (legacy, for N not divisible by 128): C = A @ W^T
// ---------------------------------------------------------------------------
template<typename TOUT>
__global__ __launch_bounds__(256) void gemm_mfma(
    const bf16* __restrict__ A, const bf16* __restrict__ W, TOUT* __restrict__ C,
    int K, int lda, int ldw, int ldc, long azs, long wzs, long czs)
{
  A += (long)blockIdx.z * azs;
  W += (long)blockIdx.z * wzs;
  C += (long)blockIdx.z * czs;
  __shared__ __align__(16) unsigned short As[8*65*8];   // 8320 B
  __shared__ __align__(16) unsigned short Ws[8*65*8];
  const int tid = threadIdx.x;
  const int m0 = blockIdx.y << 6, n0 = blockIdx.x << 6;
  const int w = tid >> 6, lane = tid & 63;
  const int quad = lane >> 4, l16 = lane & 15;

  const int r0 = tid >> 3, c80 = tid & 7;
  const int r1 = (tid + 256) >> 3;

  f32x4 acc[4];
  #pragma unroll
  for (int i = 0; i < 4; ++i) acc[i] = (f32x4){0.f,0.f,0.f,0.f};

  for (int k0 = 0; k0 < K; k0 += 64) {
    uint4 a0 = *(const uint4*)(A + (long)(m0 + r0)*lda + k0 + c80*8);
    uint4 a1 = *(const uint4*)(A + (long)(m0 + r1)*lda + k0 + c80*8);
    uint4 w0 = *(const uint4*)(W + (long)(n0 + r0)*ldw + k0 + c80*8);
    uint4 w1 = *(const uint4*)(W + (long)(n0 + r1)*ldw + k0 + c80*8);
    __syncthreads();
    *(uint4*)(As + (c80*65 + r0)*8) = a0;
    *(uint4*)(As + (c80*65 + r1)*8) = a1;
    *(uint4*)(Ws + (c80*65 + r0)*8) = w0;
    *(uint4*)(Ws + (c80*65 + r1)*8) = w1;
    __syncthreads();
    #pragma unroll
    for (int kc = 0; kc < 2; ++kc) {
      const int kcq = kc*4 + quad;
      U8 af; af.u = *(const uint4*)(As + (kcq*65 + w*16 + l16)*8);
      #pragma unroll
      for (int nt = 0; nt < 4; ++nt) {
        U8 bf_; bf_.u = *(const uint4*)(Ws + (kcq*65 + nt*16 + l16)*8);
        acc[nt] = MFMA16x32(af.s, bf_.s, acc[nt]);
      }
    }
  }
  #pragma unroll
  for (int nt = 0; nt < 4; ++nt) {
    #pragma unroll
    for (int i = 0; i < 4; ++i) {
      long row = m0 + w*16 + quad*4 + i;
      TOUT v;
      if constexpr (sizeof(TOUT) == 2) v = __float2bfloat16(acc[nt][i]);
      else                             v = acc[nt][i];
      C[row*ldc + n0 + nt*16 + l16] = v;
    }
  }
}

// ---------------------------------------------------------------------------
// gemm128: m97-structure 128x128 tile, BK=64, global_load_lds staging,
// XOR-swizzled LDS (source-side; dest linear).  C[M,N] = A[M,K] @ W[N,K]^T.
// ---------------------------------------------------------------------------
template<typename TOUT>
__global__ __launch_bounds__(256) void gemm128(
    const bf16* __restrict__ A, const bf16* __restrict__ W, TOUT* __restrict__ C,
    int K, int lda, int ldw, int ldc, long azs, long wzs, long czs)
{
  const unsigned short* Au = (const unsigned short*)A + (long)blockIdx.z * azs;
  const unsigned short* Wu = (const unsigned short*)W + (long)blockIdx.z * wzs;
  C += (long)blockIdx.z * czs;
  __shared__ __align__(16) unsigned short smem[2048 * 8];   // 32,768 B
  const int tid = threadIdx.x;
  const int m0 = blockIdx.y << 7, n0 = blockIdx.x << 7;
  const int w = tid >> 6, lane = tid & 63;
  const int quad = lane >> 4, l16 = lane & 15;
  const int wr = w >> 1, wc = w & 1;

  f32x4 acc[4][4];
  #pragma unroll
  for (int mt = 0; mt < 4; ++mt)
    #pragma unroll
    for (int nt = 0; nt < 4; ++nt) acc[mt][nt] = (f32x4){0.f,0.f,0.f,0.f};

  for (int k0 = 0; k0 < K; k0 += 64) {
    #pragma unroll
    for (int j = 0; j < 4; ++j) {
      const int u = tid + j*256;
      const int row = u >> 3, c8 = (u & 7) ^ (row & 7);
      gload16(Au + (long)(m0 + row)*lda + k0 + c8*8, smem + (j*256 + w*64)*8);
    }
    #pragma unroll
    for (int j = 0; j < 4; ++j) {
      const int u = tid + j*256;
      const int row = u >> 3, c8 = (u & 7) ^ (row & 7);
      gload16(Wu + (long)(n0 + row)*ldw + k0 + c8*8, smem + (1024 + j*256 + w*64)*8);
    }
    __syncthreads();   // DMA landed; previous-iter reads done
    #pragma unroll
    for (int kc = 0; kc < 2; ++kc) {
      const int kcq = kc*4 + quad;
      U8 af[4];
      #pragma unroll
      for (int mt = 0; mt < 4; ++mt) {
        const int row = wr*64 + mt*16 + l16;
        af[mt].u = *(const uint4*)(smem + (row*8 + (kcq ^ (row & 7)))*8);
      }
      #pragma unroll
      for (int nt = 0; nt < 4; ++nt) {
        const int rowb = wc*64 + nt*16 + l16;
        U8 bf_; bf_.u = *(const uint4*)(smem + (1024 + rowb*8 + (kcq ^ (rowb & 7)))*8);
        #pragma unroll
        for (int mt = 0; mt < 4; ++mt)
          acc[mt][nt] = MFMA16x32(af[mt].s, bf_.s, acc[mt][nt]);
      }
    }
    __syncthreads();   // all reads done before next stage overwrites
  }
  #pragma unroll
  for (int mt = 0; mt < 4; ++mt) {
    #pragma unroll
    for (int nt = 0; nt < 4; ++nt) {
      #pragma unroll
      for (int i = 0; i < 4; ++i) {
        long row = m0 + wr*64 + mt*16 + quad*4 + i;
        int  col = n0 + wc*64 + nt*16 + l16;
        TOUT v;
        if constexpr (sizeof(TOUT) == 2) v = __float2bfloat16(acc[mt][nt][i]);
        else                             v = acc[mt][nt][i];
        C[row*ldc + col] = v;
      }
    }
  }
}

// ---------------------------------------------------------------------------
// kvprep (bf16 in): RMSNorm first 512 -> ckv (bf16), RoPE last 64 -> kpe (bf16)
// ---------------------------------------------------------------------------
__global__ __launch_bounds__(64) void kvprep(
    const bf16* __restrict__ kvbuf, const float* __restrict__ wnorm,
    const float* __restrict__ cosb, const float* __restrict__ sinb,
    bf16* __restrict__ ckv, bf16* __restrict__ kpe)
{
  const int row = blockIdx.x;
  const int s = row & (S_TOK - 1);
  const int lane = threadIdx.x;
  const unsigned short* kr = (const unsigned short*)kvbuf + (long)row * 576;
  uint4 u = *(const uint4*)(kr + lane*8);
  float v[8] = { bl(u.x), bh(u.x), bl(u.y), bh(u.y), bl(u.z), bh(u.z), bl(u.w), bh(u.w) };
  float ss = 0.f;
  #pragma unroll
  for (int j = 0; j < 8; ++j) ss += v[j]*v[j];
  #pragma unroll
  for (int off = 32; off > 0; off >>= 1) ss += __shfl_down(ss, off);
  ss = __shfl(ss, 0);
  const float scl = rsqrtf(ss * (1.0f/512.0f) + 1e-6f);
  float4 w0 = *(const float4*)(wnorm + lane*8);
  float4 w1 = *(const float4*)(wnorm + lane*8 + 4);
  bf16* cd = ckv + (long)row*512 + lane*8;
  store4(cd,   v[0]*scl*w0.x, v[1]*scl*w0.y, v[2]*scl*w0.z, v[3]*scl*w0.w);
  store4(cd+4, v[4]*scl*w1.x, v[5]*scl*w1.y, v[6]*scl*w1.z, v[7]*scl*w1.w);
  if (lane < 32) {
    unsigned pe = *(const unsigned*)(kr + 512 + 2*lane);
    float xe = bl(pe), xo = bh(pe);
    float c = cosb[s*32 + lane], sn = sinb[s*32 + lane];
    ushort2 o; o.x = f2b(xe*c - xo*sn); o.y = f2b(xe*sn + xo*c);
    *(ushort2*)((unsigned short*)kpe + (long)row*64 + 2*lane) = o;
  }
}

// ---------------------------------------------------------------------------
// kpe_bcast: kpe (4096,64) -> khbuf[row, h*192+128 .. +192) for all 16 heads
// ---------------------------------------------------------------------------
__global__ __launch_bounds__(256) void kpe_bcast(const bf16* __restrict__ kpe,
                                                 bf16* __restrict__ khbuf)
{
  int gid = blockIdx.x * 256 + threadIdx.x;    // 4096*16*32
  int row = gid >> 9; int rem = gid & 511;
  int h = rem >> 5, i = rem & 31;
  unsigned pe = *(const unsigned*)((const unsigned short*)kpe + (long)row*64 + 2*i);
  *(unsigned*)((unsigned short*)khbuf + (long)row*3072 + h*192 + 128 + 2*i) = pe;
}

// ---------------------------------------------------------------------------
// ropeq: RoPE q_pe slice of qbuf IN PLACE (per head, slots 128..192)
// ---------------------------------------------------------------------------
__global__ __launch_bounds__(256) void ropeq(
    bf16* __restrict__ qbuf, const float* __restrict__ cosb,
    const float* __restrict__ sinb)
{
  int gid = blockIdx.x * 256 + threadIdx.x;       // 4096*16*32
  int row = gid >> 9; int rem = gid & 511;
  int h = rem >> 5, i = rem & 31;
  int s = row & (S_TOK - 1);
  unsigned short* p = (unsigned short*)qbuf + (long)row*3072 + h*QKD + NOPE_ + 2*i;
  unsigned pp = *(const unsigned*)p;
  float xe = bl(pp), xo = bh(pp);
  float c = cosb[s*32 + i], sn = sinb[s*32 + i];
  ushort2 u; u.x = f2b(xe*c - xo*sn); u.y = f2b(xe*sn + xo*c);
  *(ushort2*)p = u;
}

// ---------------------------------------------------------------------------
// tr_v: vbuf (b*2048+t, h*128+d) -> vT per (b,h), 32-token tiles, swizzled:
//   granule g = (b*16+h)*32768 + (t>>5)*512 + d*4 + (((t&31)>>3)^((d>>1)&3)),
//   element byte (t&7)*2.
// ---------------------------------------------------------------------------
__global__ __launch_bounds__(256) void tr_v(const bf16* __restrict__ vbuf,
                                            bf16* __restrict__ vT)
{
  const int t0 = blockIdx.x << 6, d0 = blockIdx.y << 6;
  const int b = blockIdx.z >> 4, h = blockIdx.z & 15;
  const int tid = threadIdx.x;
  __shared__ unsigned short tile[64*65];
  #pragma unroll
  for (int j = 0; j < 16; ++j) {
    int idx = tid + j*256; int r = idx >> 6, c = idx & 63;   // r=t, c=d
    tile[r*65 + c] = ((const unsigned short*)vbuf)[((long)(b*S_TOK + t0 + r))*2048 + h*128 + d0 + c];
  }
  __syncthreads();
  #pragma unroll
  for (int j = 0; j < 16; ++j) {
    int idx = tid + j*256; int r = idx >> 6, t = idx & 63;   // r: d offset, t: token offset
    int tt = t0 + t;
    int d  = d0 + r;
    long g = (long)(b*16 + h)*32768 + (long)(tt >> 5)*512 + d*4 + (((tt & 31) >> 3) ^ ((d >> 1) & 3));
    ((unsigned short*)vT)[g*8 + (tt & 7)] = tile[t*65 + r];
  }
}

// ---------------------------------------------------------------------------
// MFMA flash attention v10 — 64-token K/V tiles (half the barrier/drain
// periods of v9).  De-absorbed per-head K (192) / V (128); verified barrier
// structure (stage -> sync -> compute -> sync); all tiles active (ntiles=qt+1,
// masked strips exp to exactly 0 so P is always defined).
//
// LDS granule arenas (granule = 16 B):
//   K [0,1536):    64 t x 24 c8, g = t*24 + swz(c8,t),
//                  swz = c8<16 ? (c8&8)|((c8^t)&7) : 16+((c8^t)&7)
//   V [1536,2560): two 32-tok subtiles, g = 1536 + half*512 + d*4
//                  + (tg ^ ((d>>1)&3))
// P_s: per-wave 16 rows x 72 stride (64 cols used).
// ---------------------------------------------------------------------------
__global__ __launch_bounds__(256, 3) void attn_mfma(
    const bf16* __restrict__ qbuf,   // (4096, 16*192) rope applied in place
    const bf16* __restrict__ khbuf,  // (4096, 16*192) per-head K
    const bf16* __restrict__ vT,     // (B,16,64 tiles,512 granules) swizzled
    bf16* __restrict__ obuf)         // (4096, 2048) bf16
{
  // XCD-aware remap: xcd = phys&7; xcd 0-3 -> b=0, 4-7 -> b=1; bijective.
  const int phys = blockIdx.x;
  const int b  = (phys & 7) >> 2;
  const int r_ = ((phys & 3) << 7) | (phys >> 3);   // [0,512)
  const int h  = r_ >> 5;
  const int qt = r_ & 31;
  const int q0 = qt << 6;
  const int tid = threadIdx.x;
  const int w = tid >> 6, lane = tid & 63;
  const int quad = lane >> 4, l16 = lane & 15;

  __shared__ __align__(16) unsigned short smem[2560 * 8];    // 40,960 B
  __shared__ __align__(16) unsigned short P_s[4 * 16 * 72];  //  9,216 B

  const unsigned short* kh_b = (const unsigned short*)khbuf + (long)b*S_TOK*3072 + h*192;
  const unsigned short* vt_b = (const unsigned short*)vT + (long)(b*16 + h)*32768*8;
  unsigned short* Pw = P_s + w*1152;

  // ---- Q fragments: 6 K-chunks of 32 (128 nope + 64 roped pe, contiguous)
  const long qrow = (long)b*S_TOK + q0 + w*16 + l16;
  short8 qf[6];
  {
    const unsigned short* qlp = (const unsigned short*)qbuf + qrow*3072 + h*192 + quad*8;
    #pragma unroll
    for (int kc = 0; kc < 6; ++kc) { U8 t; t.u = *(const uint4*)(qlp + kc*32); qf[kc] = t.s; }
  }

  f32x4 acc[8];
  #pragma unroll
  for (int i = 0; i < 8; ++i) acc[i] = (f32x4){0.f,0.f,0.f,0.f};
  float mi[4] = {NEG_BIG,NEG_BIG,NEG_BIG,NEG_BIG};
  float li[4] = {0.f,0.f,0.f,0.f};

  const int ntiles = qt + 1;          // 64-token tiles; all active

  #pragma unroll 1
  for (int tile = 0; tile < ntiles; ++tile) {
    const int t0 = tile << 6;
    // ---- stage K-tile (6 DMA) + V-tile (4 DMA), all coalesced 16B/lane ----
    #pragma unroll
    for (int j = 0; j < 6; ++j) {
      const int u = tid + j*256;
      const int t = u / 24, c8p = u - t*24;
      const int c8 = (c8p < 16) ? ((c8p & 8) | ((c8p ^ t) & 7))
                                : (16 + ((c8p ^ t) & 7));
      gload16(kh_b + (long)(t0 + t)*3072 + c8*8, smem + (j*256 + w*64)*8);
    }
    #pragma unroll
    for (int j = 0; j < 4; ++j) {
      const unsigned short* vt = vt_b + (long)(2*tile + (j >> 1)) * 512 * 8;
      const int u = (tid + j*256) & 511;
      gload16(vt + (long)u*8, smem + (1536 + j*256 + w*64)*8);
    }
    __syncthreads();   // drains vmcnt: DMA complete, previous reads done

    // ---- scores: four 16x16 C-strips (token quarters), 6 kc each ----
    f32x4 sc0 = (f32x4){0.f,0.f,0.f,0.f}, sc1 = sc0, sc2 = sc0, sc3 = sc0;
    #pragma unroll
    for (int kc = 0; kc < 6; ++kc) {
      const int kcq = kc*4 + quad;
      const int sw = (kcq < 16) ? ((kcq & 8) | ((kcq ^ l16) & 7))
                                : (16 + ((kcq ^ l16) & 7));
      U8 b0; b0.u = *(const uint4*)(smem + ((     l16)*24 + sw)*8);
      U8 b1; b1.u = *(const uint4*)(smem + ((16 + l16)*24 + sw)*8);
      U8 b2; b2.u = *(const uint4*)(smem + ((32 + l16)*24 + sw)*8);
      U8 b3; b3.u = *(const uint4*)(smem + ((48 + l16)*24 + sw)*8);
      sc0 = MFMA16x32(qf[kc], b0.s, sc0);
      sc1 = MFMA16x32(qf[kc], b1.s, sc1);
      sc2 = MFMA16x32(qf[kc], b2.s, sc2);
      sc3 = MFMA16x32(qf[kc], b3.s, sc3);
    }
    // ---- online softmax over 64 cols with defer-max ----
    float sv0[4], sv1[4], sv2[4], sv3[4], tm[4];
    #pragma unroll
    for (int i = 0; i < 4; ++i) {
      int qg = q0 + w*16 + quad*4 + i;
      sv0[i] = (t0      + l16 <= qg) ? sc0[i]*SCALE_F : NEG_BIG;
      sv1[i] = (t0 + 16 + l16 <= qg) ? sc1[i]*SCALE_F : NEG_BIG;
      sv2[i] = (t0 + 32 + l16 <= qg) ? sc2[i]*SCALE_F : NEG_BIG;
      sv3[i] = (t0 + 48 + l16 <= qg) ? sc3[i]*SCALE_F : NEG_BIG;
      tm[i] = fmaxf(fmaxf(sv0[i], sv1[i]), fmaxf(sv2[i], sv3[i]));
    }
    #pragma unroll
    for (int d = 1; d < 16; d <<= 1) {
      #pragma unroll
      for (int i = 0; i < 4; ++i) tm[i] = fmaxf(tm[i], __shfl_xor(tm[i], d));
    }
    bool small = (tm[0] - mi[0] <= DEFER_THR) && (tm[1] - mi[1] <= DEFER_THR)
              && (tm[2] - mi[2] <= DEFER_THR) && (tm[3] - mi[3] <= DEFER_THR);
    if (!__all(small)) {
      float al[4];
      #pragma unroll
      for (int i = 0; i < 4; ++i) {
        float mx = fmaxf(mi[i], tm[i]);
        al[i] = __expf(mi[i] - mx);
        mi[i] = mx;
        li[i] *= al[i];
      }
      #pragma unroll
      for (int nt = 0; nt < 8; ++nt) {
        #pragma unroll
        for (int i = 0; i < 4; ++i) acc[nt][i] *= al[i];
      }
    }
    float rs[4];
    #pragma unroll
    for (int i = 0; i < 4; ++i) {
      float p0 = __expf(sv0[i] - mi[i]);
      float p1 = __expf(sv1[i] - mi[i]);
      float p2 = __expf(sv2[i] - mi[i]);
      float p3 = __expf(sv3[i] - mi[i]);
      rs[i] = (p0 + p1) + (p2 + p3);
      const int rb = (quad*4+i)*72 + l16;
      Pw[rb]      = f2b(p0);
      Pw[rb + 16] = f2b(p1);
      Pw[rb + 32] = f2b(p2);
      Pw[rb + 48] = f2b(p3);
    }
    #pragma unroll
    for (int d = 1; d < 16; d <<= 1) {
      #pragma unroll
      for (int i = 0; i < 4; ++i) rs[i] += __shfl_xor(rs[i], d);
    }
    #pragma unroll
    for (int i = 0; i < 4; ++i) li[i] += rs[i];
    // ---- PV: A = P (LDS roundtrip), B = V^T subtiles, 2x8 MFMA ----
    #pragma unroll
    for (int half = 0; half < 2; ++half) {
      U8 ap; ap.u = *(const uint4*)(Pw + l16*72 + half*32 + quad*8);
      #pragma unroll
      for (int nt = 0; nt < 8; ++nt) {
        const int c = nt*16 + l16;
        U8 bv; bv.u = *(const uint4*)(smem +
                       (1536 + half*512 + c*4 + (quad ^ ((c >> 1) & 3)))*8);
        acc[nt] = MFMA16x32(ap.s, bv.s, acc[nt]);
      }
    }
    __syncthreads();   // smem reads done before next tile's DMA
  }

  // ---- epilogue: normalize, write O directly (no latent projection) ----
  float linv[4];
  #pragma unroll
  for (int i = 0; i < 4; ++i) linv[i] = 1.0f / li[i];
  #pragma unroll
  for (int nt = 0; nt < 8; ++nt) {
    #pragma unroll
    for (int i = 0; i < 4; ++i)
      ((unsigned short*)obuf)[((long)b*S_TOK + q0 + w*16 + quad*4 + i)*2048
                              + h*128 + nt*16 + l16] = f2b(acc[nt][i] * linv[i]);
  }
}

// ---------------------------------------------------------------------------
extern "C" void kernel_launch(void* const* d_in, const int* in_sizes, int n_in,
                              void* d_out, int out_size, void* d_ws, size_t ws_size,
                              hipStream_t stream)
{
  const float* x     = (const float*)d_in[0];
  const float* wq    = (const float*)d_in[1];
  const float* wkv_a = (const float*)d_in[2];
  const float* kvnw  = (const float*)d_in[3];
  const float* wkv_b = (const float*)d_in[4];
  const float* wo    = (const float*)d_in[5];
  const float* cosb  = (const float*)d_in[6];
  const float* sinb  = (const float*)d_in[7];
  float* out = (float*)d_out;

  size_t off = 0;
  char* wsb = (char*)d_ws;
  bf16* xb    = (bf16*)(wsb + off); off += (size_t)NROWS * 2048 * 2;   // 16.8 MB
  bf16* wqb   = (bf16*)(wsb + off); off += (size_t)3072 * 2048 * 2;    // 12.6 MB
  bf16* wab   = (bf16*)(wsb + off); off += (size_t)576  * 2048 * 2;    //  2.4 MB
  bf16* wob   = (bf16*)(wsb + off); off += (size_t)2048 * 2048 * 2;    //  8.4 MB
  bf16* wbkb  = (bf16*)(wsb + off); off += (size_t)1048576 * 2;        //  2.1 MB
  bf16* wbvb  = (bf16*)(wsb + off); off += (size_t)1048576 * 2;        //  2.1 MB
  bf16* qbuf  = (bf16*)(wsb + off); off += (size_t)NROWS * 3072 * 2;   // 25.2 MB
  bf16* kvbuf = (bf16*)(wsb + off); off += (size_t)NROWS * 576  * 2;   //  4.7 MB
  bf16* ckvb  = (bf16*)(wsb + off); off += (size_t)NROWS * 512  * 2;   //  4.2 MB
  bf16* kpeb  = (bf16*)(wsb + off); off += (size_t)NROWS * 64   * 2;   //  0.5 MB
  bf16* khbuf = (bf16*)(wsb + off); off += (size_t)NROWS * 3072 * 2;   // 25.2 MB
  bf16* vbuf  = (bf16*)(wsb + off); off += (size_t)NROWS * 2048 * 2;   // 16.8 MB
  bf16* vTb   = (bf16*)(wsb + off); off += (size_t)NROWS * 2048 * 2;   // 16.8 MB
  bf16* obuf  = (bf16*)(wsb + off); off += (size_t)NROWS * 2048 * 2;   // 16.8 MB

  dim3 blk(256);
  // input/weight conversions
  cvt_bf16<<<dim3(8388608/1024),  blk, 0, stream>>>(x,     xb,  8388608);
  cvt_bf16<<<dim3(6291456/1024),  blk, 0, stream>>>(wq,    wqb, 6291456);
  cvt_bf16<<<dim3(1179648/1024),  blk, 0, stream>>>(wkv_a, wab, 1179648);
  cvt_bf16<<<dim3(4194304/1024),  blk, 0, stream>>>(wo,    wob, 4194304);
  wbhalf_cvt<<<dim3(4096), blk, 0, stream>>>(wkv_b, wbkb, 0);      // K half
  wbhalf_cvt<<<dim3(4096), blk, 0, stream>>>(wkv_b, wbvb, NOPE_);  // V half
  // q = x @ wq^T (128-tile), then RoPE q_pe slices in place
  gemm128<bf16><<<dim3(3072/128, NROWS/128, 1), blk, 0, stream>>>(
      xb, wqb, qbuf, 2048, 2048, 2048, 3072, 0, 0, 0);
  ropeq<<<dim3(8192), blk, 0, stream>>>(qbuf, cosb, sinb);
  // kv = x @ wkv_a^T (N=576 -> legacy 64-tile); rmsnorm + rope
  gemm_mfma<bf16><<<dim3(576/64, NROWS/64, 1), blk, 0, stream>>>(
      xb, wab, kvbuf, 2048, 2048, 2048, 576, 0, 0, 0);
  kvprep<<<dim3(NROWS), dim3(64), 0, stream>>>(kvbuf, kvnw, cosb, sinb, ckvb, kpeb);
  // de-absorbed per-head K/V:  K_h = ckv @ wbk[h]^T (+ kpe),  V_h = ckv @ wbv[h]^T
  kpe_bcast<<<dim3(8192), blk, 0, stream>>>(kpeb, khbuf);
  gemm128<bf16><<<dim3(1, NROWS/128, NH), blk, 0, stream>>>(
      ckvb, wbkb, khbuf, 512, 512, 512, 3072, 0, (long)128*512, (long)192);
  gemm128<bf16><<<dim3(1, NROWS/128, NH), blk, 0, stream>>>(
      ckvb, wbvb, vbuf, 512, 512, 512, 2048, 0, (long)128*512, (long)128);
  tr_v<<<dim3(S_TOK/64, 2, 32), blk, 0, stream>>>(vbuf, vTb);
  // standard MHA flash attention (192-dim QK, 128-dim PV), 64-token tiles
  attn_mfma<<<dim3(1024), blk, 0, stream>>>(qbuf, khbuf, vTb, obuf);
  // out = o @ wo^T (128-tile, f32 out)
  gemm128<float><<<dim3(2048/128, NROWS/128, 1), blk, 0, stream>>>(
      obuf, wob, out, 2048, 2048, 2048, 2048, 0, 0, 0);
}

// Round 9
// 441.961 us; speedup vs baseline: 2.4997x; 1.0329x over previous
//
#include <hip/hip_runtime.h>
#include <hip/hip_bf16.h>

typedef __hip_bfloat16 bf16;
typedef __attribute__((ext_vector_type(8))) short short8;   // 8 bf16 = 4 VGPRs (MFMA A/B frag)
typedef __attribute__((ext_vector_type(4))) float f32x4;    // MFMA C/D frag

#define S_TOK   2048
#define NROWS   4096        // B*S
#define NH      16
#define QKD     192
#define NOPE_   128
#define ROPE_   64
#define VDIM_   128
#define RANK    512
#define SCALE_F 0.07216878364870323f   // 192^-0.5
#define NEG_BIG -3.0e38f
#define DEFER_THR 8.0f

__device__ __forceinline__ float bl(unsigned u){ union{unsigned i; float f;} t; t.i = u << 16; return t.f; }
__device__ __forceinline__ float bh(unsigned u){ union{unsigned i; float f;} t; t.i = u & 0xffff0000u; return t.f; }
__device__ __forceinline__ unsigned short f2b(float f){
  bf16 h = __float2bfloat16(f);
  return *reinterpret_cast<unsigned short*>(&h);
}
__device__ __forceinline__ void store4(bf16* p, float a, float b, float c, float d){
  ushort4 u; u.x=f2b(a); u.y=f2b(b); u.z=f2b(c); u.w=f2b(d);
  *(ushort4*)p = u;
}
union U8 { uint4 u; short8 s; };
#define MFMA16x32(a,b,c) __builtin_amdgcn_mfma_f32_16x16x32_bf16(a,b,c,0,0,0)

// async global -> LDS DMA, 16 B per lane; dest wave-uniform base + lane*16.
__device__ __forceinline__ void gload16(const unsigned short* g, unsigned short* l)
{
  __builtin_amdgcn_global_load_lds(
      (const __attribute__((address_space(1))) unsigned int*)g,
      (__attribute__((address_space(3))) unsigned int*)l,
      16, 0, 0);
}

// ---------------------------------------------------------------------------
// cvt_bf16: f32 -> bf16 elementwise (n multiple of 1024)
// ---------------------------------------------------------------------------
__global__ __launch_bounds__(256) void cvt_bf16(const float* __restrict__ src,
                                                bf16* __restrict__ dst, int n)
{
  int g = (blockIdx.x * 256 + threadIdx.x) * 4;
  if (g < n) {
    float4 v = *(const float4*)(src + g);
    store4(dst + g, v.x, v.y, v.z, v.w);
  }
}

// ---------------------------------------------------------------------------
// gemm128: m97-structure 128x128 tile, BK=64, global_load_lds staging,
// XOR-swizzled LDS (source-side; dest linear).  C[M,N] = A[M,K] @ W[N,K]^T.
// Ncols guards the C-write for N not multiple of 128 (staging may read OOB
// W rows -> lands in adjacent workspace, defined memory, results masked).
// ---------------------------------------------------------------------------
template<typename TOUT>
__global__ __launch_bounds__(256) void gemm128(
    const bf16* __restrict__ A, const bf16* __restrict__ W, TOUT* __restrict__ C,
    int K, int lda, int ldw, int ldc, int Ncols, long azs, long wzs, long czs)
{
  const unsigned short* Au = (const unsigned short*)A + (long)blockIdx.z * azs;
  const unsigned short* Wu = (const unsigned short*)W + (long)blockIdx.z * wzs;
  C += (long)blockIdx.z * czs;
  __shared__ __align__(16) unsigned short smem[2048 * 8];   // 32,768 B
  const int tid = threadIdx.x;
  const int m0 = blockIdx.y << 7, n0 = blockIdx.x << 7;
  const int w = tid >> 6, lane = tid & 63;
  const int quad = lane >> 4, l16 = lane & 15;
  const int wr = w >> 1, wc = w & 1;

  f32x4 acc[4][4];
  #pragma unroll
  for (int mt = 0; mt < 4; ++mt)
    #pragma unroll
    for (int nt = 0; nt < 4; ++nt) acc[mt][nt] = (f32x4){0.f,0.f,0.f,0.f};

  for (int k0 = 0; k0 < K; k0 += 64) {
    #pragma unroll
    for (int j = 0; j < 4; ++j) {
      const int u = tid + j*256;
      const int row = u >> 3, c8 = (u & 7) ^ (row & 7);
      gload16(Au + (long)(m0 + row)*lda + k0 + c8*8, smem + (j*256 + w*64)*8);
    }
    #pragma unroll
    for (int j = 0; j < 4; ++j) {
      const int u = tid + j*256;
      const int row = u >> 3, c8 = (u & 7) ^ (row & 7);
      gload16(Wu + (long)(n0 + row)*ldw + k0 + c8*8, smem + (1024 + j*256 + w*64)*8);
    }
    __syncthreads();   // DMA landed; previous-iter reads done
    #pragma unroll
    for (int kc = 0; kc < 2; ++kc) {
      const int kcq = kc*4 + quad;
      U8 af[4];
      #pragma unroll
      for (int mt = 0; mt < 4; ++mt) {
        const int row = wr*64 + mt*16 + l16;
        af[mt].u = *(const uint4*)(smem + (row*8 + (kcq ^ (row & 7)))*8);
      }
      #pragma unroll
      for (int nt = 0; nt < 4; ++nt) {
        const int rowb = wc*64 + nt*16 + l16;
        U8 bf_; bf_.u = *(const uint4*)(smem + (1024 + rowb*8 + (kcq ^ (rowb & 7)))*8);
        #pragma unroll
        for (int mt = 0; mt < 4; ++mt)
          acc[mt][nt] = MFMA16x32(af[mt].s, bf_.s, acc[mt][nt]);
      }
    }
    __syncthreads();   // all reads done before next stage overwrites
  }
  #pragma unroll
  for (int mt = 0; mt < 4; ++mt) {
    #pragma unroll
    for (int nt = 0; nt < 4; ++nt) {
      const int col = n0 + wc*64 + nt*16 + l16;
      if (col < Ncols) {
        #pragma unroll
        for (int i = 0; i < 4; ++i) {
          long row = m0 + wr*64 + mt*16 + quad*4 + i;
          TOUT v;
          if constexpr (sizeof(TOUT) == 2) v = __float2bfloat16(acc[mt][nt][i]);
          else                             v = acc[mt][nt][i];
          C[row*ldc + col] = v;
        }
      }
    }
  }
}

// ---------------------------------------------------------------------------
// kvprep (bf16 in): RMSNorm first 512 -> ckv (bf16), RoPE last 64 -> kpe (bf16)
// ---------------------------------------------------------------------------
__global__ __launch_bounds__(64) void kvprep(
    const bf16* __restrict__ kvbuf, const float* __restrict__ wnorm,
    const float* __restrict__ cosb, const float* __restrict__ sinb,
    bf16* __restrict__ ckv, bf16* __restrict__ kpe)
{
  const int row = blockIdx.x;
  const int s = row & (S_TOK - 1);
  const int lane = threadIdx.x;
  const unsigned short* kr = (const unsigned short*)kvbuf + (long)row * 576;
  uint4 u = *(const uint4*)(kr + lane*8);
  float v[8] = { bl(u.x), bh(u.x), bl(u.y), bh(u.y), bl(u.z), bh(u.z), bl(u.w), bh(u.w) };
  float ss = 0.f;
  #pragma unroll
  for (int j = 0; j < 8; ++j) ss += v[j]*v[j];
  #pragma unroll
  for (int off = 32; off > 0; off >>= 1) ss += __shfl_down(ss, off);
  ss = __shfl(ss, 0);
  const float scl = rsqrtf(ss * (1.0f/512.0f) + 1e-6f);
  float4 w0 = *(const float4*)(wnorm + lane*8);
  float4 w1 = *(const float4*)(wnorm + lane*8 + 4);
  bf16* cd = ckv + (long)row*512 + lane*8;
  store4(cd,   v[0]*scl*w0.x, v[1]*scl*w0.y, v[2]*scl*w0.z, v[3]*scl*w0.w);
  store4(cd+4, v[4]*scl*w1.x, v[5]*scl*w1.y, v[6]*scl*w1.z, v[7]*scl*w1.w);
  if (lane < 32) {
    unsigned pe = *(const unsigned*)(kr + 512 + 2*lane);
    float xe = bl(pe), xo = bh(pe);
    float c = cosb[s*32 + lane], sn = sinb[s*32 + lane];
    ushort2 o; o.x = f2b(xe*c - xo*sn); o.y = f2b(xe*sn + xo*c);
    *(ushort2*)((unsigned short*)kpe + (long)row*64 + 2*lane) = o;
  }
}

// ---------------------------------------------------------------------------
// ropeq: RoPE q_pe slice of qbuf IN PLACE (per head, slots 128..192)
// ---------------------------------------------------------------------------
__global__ __launch_bounds__(256) void ropeq(
    bf16* __restrict__ qbuf, const float* __restrict__ cosb,
    const float* __restrict__ sinb)
{
  int gid = blockIdx.x * 256 + threadIdx.x;       // 4096*16*32
  int row = gid >> 9; int rem = gid & 511;
  int h = rem >> 5, i = rem & 31;
  int s = row & (S_TOK - 1);
  unsigned short* p = (unsigned short*)qbuf + (long)row*3072 + h*QKD + NOPE_ + 2*i;
  unsigned pp = *(const unsigned*)p;
  float xe = bl(pp), xo = bh(pp);
  float c = cosb[s*32 + i], sn = sinb[s*32 + i];
  ushort2 u; u.x = f2b(xe*c - xo*sn); u.y = f2b(xe*sn + xo*c);
  *(ushort2*)p = u;
}

// ---------------------------------------------------------------------------
// tr_v: khv V-half (row, h*256+128+d) -> vT per (b,h), 32-token tiles,
// swizzled: granule g = (b*16+h)*32768 + (t>>5)*512 + d*4
//           + (((t&31)>>3)^((d>>1)&3)),  element byte (t&7)*2.
// ---------------------------------------------------------------------------
__global__ __launch_bounds__(256) void tr_v(const bf16* __restrict__ khv,
                                            bf16* __restrict__ vT)
{
  const int t0 = blockIdx.x << 6, d0 = blockIdx.y << 6;
  const int b = blockIdx.z >> 4, h = blockIdx.z & 15;
  const int tid = threadIdx.x;
  __shared__ unsigned short tile[64*65];
  #pragma unroll
  for (int j = 0; j < 16; ++j) {
    int idx = tid + j*256; int r = idx >> 6, c = idx & 63;   // r=t, c=d
    tile[r*65 + c] = ((const unsigned short*)khv)[((long)(b*S_TOK + t0 + r))*4096
                                                  + h*256 + 128 + d0 + c];
  }
  __syncthreads();
  #pragma unroll
  for (int j = 0; j < 16; ++j) {
    int idx = tid + j*256; int r = idx >> 6, t = idx & 63;   // r: d offset, t: token offset
    int tt = t0 + t;
    int d  = d0 + r;
    long g = (long)(b*16 + h)*32768 + (long)(tt >> 5)*512 + d*4 + (((tt & 31) >> 3) ^ ((d >> 1) & 3));
    ((unsigned short*)vT)[g*8 + (tt & 7)] = tile[t*65 + r];
  }
}

// ---------------------------------------------------------------------------
// MFMA flash attention v11 — 64-token K/V tiles; K-nope staged from fused khv
// buffer, kpe staged directly from kpeb (no broadcast buffer).  Verified
// barrier structure; all tiles active (masked strips exp to exactly 0).
//
// LDS granule arenas (granule = 16 B):
//   K [0,1536):    64 t x 24 c8, g = t*24 + swz(c8,t),
//                  swz = c8<16 ? (c8&8)|((c8^t)&7) : 16+((c8^t)&7)
//                  content: c8<16 from khv nope, c8>=16 from kpeb
//   V [1536,2560): two 32-tok subtiles, g = 1536 + half*512 + d*4
//                  + (tg ^ ((d>>1)&3))
// P_s: per-wave 16 rows x 72 stride (64 cols used).
// ---------------------------------------------------------------------------
__global__ __launch_bounds__(256, 3) void attn_mfma(
    const bf16* __restrict__ qbuf,   // (4096, 16*192) rope applied in place
    const bf16* __restrict__ khv,    // (4096, 16*256) per-head K|V fused
    const bf16* __restrict__ kpe,    // (4096, 64) shared pe
    const bf16* __restrict__ vT,     // (B,16,64 tiles,512 granules) swizzled
    bf16* __restrict__ obuf)         // (4096, 2048) bf16
{
  // XCD-aware remap: xcd = phys&7; xcd 0-3 -> b=0, 4-7 -> b=1; bijective.
  const int phys = blockIdx.x;
  const int b  = (phys & 7) >> 2;
  const int r_ = ((phys & 3) << 7) | (phys >> 3);   // [0,512)
  const int h  = r_ >> 5;
  const int qt = r_ & 31;
  const int q0 = qt << 6;
  const int tid = threadIdx.x;
  const int w = tid >> 6, lane = tid & 63;
  const int quad = lane >> 4, l16 = lane & 15;

  __shared__ __align__(16) unsigned short smem[2560 * 8];    // 40,960 B
  __shared__ __align__(16) unsigned short P_s[4 * 16 * 72];  //  9,216 B

  const unsigned short* kh_b  = (const unsigned short*)khv + (long)b*S_TOK*4096 + h*256;
  const unsigned short* kpe_b = (const unsigned short*)kpe + (long)b*S_TOK*64;
  const unsigned short* vt_b  = (const unsigned short*)vT + (long)(b*16 + h)*32768*8;
  unsigned short* Pw = P_s + w*1152;

  // ---- Q fragments: 6 K-chunks of 32 (128 nope + 64 roped pe, contiguous)
  const long qrow = (long)b*S_TOK + q0 + w*16 + l16;
  short8 qf[6];
  {
    const unsigned short* qlp = (const unsigned short*)qbuf + qrow*3072 + h*192 + quad*8;
    #pragma unroll
    for (int kc = 0; kc < 6; ++kc) { U8 t; t.u = *(const uint4*)(qlp + kc*32); qf[kc] = t.s; }
  }

  f32x4 acc[8];
  #pragma unroll
  for (int i = 0; i < 8; ++i) acc[i] = (f32x4){0.f,0.f,0.f,0.f};
  float mi[4] = {NEG_BIG,NEG_BIG,NEG_BIG,NEG_BIG};
  float li[4] = {0.f,0.f,0.f,0.f};

  const int ntiles = qt + 1;          // 64-token tiles; all active

  #pragma unroll 1
  for (int tile = 0; tile < ntiles; ++tile) {
    const int t0 = tile << 6;
    // ---- stage K-tile (6 DMA: nope from khv, pe from kpeb via ptr-select)
    #pragma unroll
    for (int j = 0; j < 6; ++j) {
      const int u = tid + j*256;
      const int t = u / 24, c8p = u - t*24;
      const int cK = (c8p & 8) | ((c8p ^ t) & 7);
      const int cP = (c8p ^ t) & 7;
      const unsigned short* srcK = kh_b  + (long)(t0 + t)*4096 + cK*8;
      const unsigned short* srcP = kpe_b + (long)(t0 + t)*64   + cP*8;
      gload16((c8p < 16) ? srcK : srcP, smem + (j*256 + w*64)*8);
    }
    // ---- stage V-tile (4 DMA), pure linear ----
    #pragma unroll
    for (int j = 0; j < 4; ++j) {
      const unsigned short* vt = vt_b + (long)(2*tile + (j >> 1)) * 512 * 8;
      const int u = (tid + j*256) & 511;
      gload16(vt + (long)u*8, smem + (1536 + j*256 + w*64)*8);
    }
    __syncthreads();   // drains vmcnt: DMA complete, previous reads done

    // ---- scores: four 16x16 C-strips (token quarters), 6 kc each ----
    f32x4 sc0 = (f32x4){0.f,0.f,0.f,0.f}, sc1 = sc0, sc2 = sc0, sc3 = sc0;
    #pragma unroll
    for (int kc = 0; kc < 6; ++kc) {
      const int kcq = kc*4 + quad;
      const int sw = (kcq < 16) ? ((kcq & 8) | ((kcq ^ l16) & 7))
                                : (16 + ((kcq ^ l16) & 7));
      U8 b0; b0.u = *(const uint4*)(smem + ((     l16)*24 + sw)*8);
      U8 b1; b1.u = *(const uint4*)(smem + ((16 + l16)*24 + sw)*8);
      U8 b2; b2.u = *(const uint4*)(smem + ((32 + l16)*24 + sw)*8);
      U8 b3; b3.u = *(const uint4*)(smem + ((48 + l16)*24 + sw)*8);
      sc0 = MFMA16x32(qf[kc], b0.s, sc0);
      sc1 = MFMA16x32(qf[kc], b1.s, sc1);
      sc2 = MFMA16x32(qf[kc], b2.s, sc2);
      sc3 = MFMA16x32(qf[kc], b3.s, sc3);
    }
    // ---- online softmax over 64 cols with defer-max ----
    float sv0[4], sv1[4], sv2[4], sv3[4], tm[4];
    #pragma unroll
    for (int i = 0; i < 4; ++i) {
      int qg = q0 + w*16 + quad*4 + i;
      sv0[i] = (t0      + l16 <= qg) ? sc0[i]*SCALE_F : NEG_BIG;
      sv1[i] = (t0 + 16 + l16 <= qg) ? sc1[i]*SCALE_F : NEG_BIG;
      sv2[i] = (t0 + 32 + l16 <= qg) ? sc2[i]*SCALE_F : NEG_BIG;
      sv3[i] = (t0 + 48 + l16 <= qg) ? sc3[i]*SCALE_F : NEG_BIG;
      tm[i] = fmaxf(fmaxf(sv0[i], sv1[i]), fmaxf(sv2[i], sv3[i]));
    }
    #pragma unroll
    for (int d = 1; d < 16; d <<= 1) {
      #pragma unroll
      for (int i = 0; i < 4; ++i) tm[i] = fmaxf(tm[i], __shfl_xor(tm[i], d));
    }
    bool small = (tm[0] - mi[0] <= DEFER_THR) && (tm[1] - mi[1] <= DEFER_THR)
              && (tm[2] - mi[2] <= DEFER_THR) && (tm[3] - mi[3] <= DEFER_THR);
    if (!__all(small)) {
      float al[4];
      #pragma unroll
      for (int i = 0; i < 4; ++i) {
        float mx = fmaxf(mi[i], tm[i]);
        al[i] = __expf(mi[i] - mx);
        mi[i] = mx;
        li[i] *= al[i];
      }
      #pragma unroll
      for (int nt = 0; nt < 8; ++nt) {
        #pragma unroll
        for (int i = 0; i < 4; ++i) acc[nt][i] *= al[i];
      }
    }
    float rs[4];
    #pragma unroll
    for (int i = 0; i < 4; ++i) {
      float p0 = __expf(sv0[i] - mi[i]);
      float p1 = __expf(sv1[i] - mi[i]);
      float p2 = __expf(sv2[i] - mi[i]);
      float p3 = __expf(sv3[i] - mi[i]);
      rs[i] = (p0 + p1) + (p2 + p3);
      const int rb = (quad*4+i)*72 + l16;
      Pw[rb]      = f2b(p0);
      Pw[rb + 16] = f2b(p1);
      Pw[rb + 32] = f2b(p2);
      Pw[rb + 48] = f2b(p3);
    }
    #pragma unroll
    for (int d = 1; d < 16; d <<= 1) {
      #pragma unroll
      for (int i = 0; i < 4; ++i) rs[i] += __shfl_xor(rs[i], d);
    }
    #pragma unroll
    for (int i = 0; i < 4; ++i) li[i] += rs[i];
    // ---- PV: A = P (LDS roundtrip), B = V^T subtiles, 2x8 MFMA ----
    #pragma unroll
    for (int half = 0; half < 2; ++half) {
      U8 ap; ap.u = *(const uint4*)(Pw + l16*72 + half*32 + quad*8);
      #pragma unroll
      for (int nt = 0; nt < 8; ++nt) {
        const int c = nt*16 + l16;
        U8 bv; bv.u = *(const uint4*)(smem +
                       (1536 + half*512 + c*4 + (quad ^ ((c >> 1) & 3)))*8);
        acc[nt] = MFMA16x32(ap.s, bv.s, acc[nt]);
      }
    }
    __syncthreads();   // smem reads done before next tile's DMA
  }

  // ---- epilogue: normalize, write O directly (no latent projection) ----
  float linv[4];
  #pragma unroll
  for (int i = 0; i < 4; ++i) linv[i] = 1.0f / li[i];
  #pragma unroll
  for (int nt = 0; nt < 8; ++nt) {
    #pragma unroll
    for (int i = 0; i < 4; ++i)
      ((unsigned short*)obuf)[((long)b*S_TOK + q0 + w*16 + quad*4 + i)*2048
                              + h*128 + nt*16 + l16] = f2b(acc[nt][i] * linv[i]);
  }
}

// ---------------------------------------------------------------------------
extern "C" void kernel_launch(void* const* d_in, const int* in_sizes, int n_in,
                              void* d_out, int out_size, void* d_ws, size_t ws_size,
                              hipStream_t stream)
{
  const float* x     = (const float*)d_in[0];
  const float* wq    = (const float*)d_in[1];
  const float* wkv_a = (const float*)d_in[2];
  const float* kvnw  = (const float*)d_in[3];
  const float* wkv_b = (const float*)d_in[4];
  const float* wo    = (const float*)d_in[5];
  const float* cosb  = (const float*)d_in[6];
  const float* sinb  = (const float*)d_in[7];
  float* out = (float*)d_out;

  size_t off = 0;
  char* wsb = (char*)d_ws;
  bf16* xb    = (bf16*)(wsb + off); off += (size_t)NROWS * 2048 * 2;   // 16.8 MB
  bf16* wqb   = (bf16*)(wsb + off); off += (size_t)3072 * 2048 * 2;    // 12.6 MB
  bf16* wab   = (bf16*)(wsb + off); off += (size_t)576  * 2048 * 2;    //  2.4 MB
  bf16* wob   = (bf16*)(wsb + off); off += (size_t)2048 * 2048 * 2;    //  8.4 MB
  bf16* wkvbb = (bf16*)(wsb + off); off += (size_t)4096 * 512 * 2;     //  4.2 MB
  bf16* qbuf  = (bf16*)(wsb + off); off += (size_t)NROWS * 3072 * 2;   // 25.2 MB
  bf16* kvbuf = (bf16*)(wsb + off); off += (size_t)NROWS * 576  * 2;   //  4.7 MB
  bf16* ckvb  = (bf16*)(wsb + off); off += (size_t)NROWS * 512  * 2;   //  4.2 MB
  bf16* kpeb  = (bf16*)(wsb + off); off += (size_t)NROWS * 64   * 2;   //  0.5 MB
  bf16* khv   = (bf16*)(wsb + off); off += (size_t)NROWS * 4096 * 2;   // 33.6 MB
  bf16* vTb   = (bf16*)(wsb + off); off += (size_t)NROWS * 2048 * 2;   // 16.8 MB
  bf16* obuf  = (bf16*)(wsb + off); off += (size_t)NROWS * 2048 * 2;   // 16.8 MB

  dim3 blk(256);
  // input/weight conversions
  cvt_bf16<<<dim3(8388608/1024),  blk, 0, stream>>>(x,     xb,    8388608);
  cvt_bf16<<<dim3(6291456/1024),  blk, 0, stream>>>(wq,    wqb,   6291456);
  cvt_bf16<<<dim3(1179648/1024),  blk, 0, stream>>>(wkv_a, wab,   1179648);
  cvt_bf16<<<dim3(4194304/1024),  blk, 0, stream>>>(wo,    wob,   4194304);
  cvt_bf16<<<dim3(2097152/1024),  blk, 0, stream>>>(wkv_b, wkvbb, 2097152);
  // q = x @ wq^T (128-tile), then RoPE q_pe slices in place
  gemm128<bf16><<<dim3(3072/128, NROWS/128, 1), blk, 0, stream>>>(
      xb, wqb, qbuf, 2048, 2048, 2048, 3072, 3072, 0, 0, 0);
  ropeq<<<dim3(8192), blk, 0, stream>>>(qbuf, cosb, sinb);
  // kv = x @ wkv_a^T (N=576, guarded 128-tile); rmsnorm + rope
  gemm128<bf16><<<dim3(5, NROWS/128, 1), blk, 0, stream>>>(
      xb, wab, kvbuf, 2048, 2048, 2048, 576, 576, 0, 0, 0);
  kvprep<<<dim3(NROWS), dim3(64), 0, stream>>>(kvbuf, kvnw, cosb, sinb, ckvb, kpeb);
  // fused per-head K|V: khv = ckv @ wkv_b^T  (row, h*256 + {K:0..128, V:128..256})
  gemm128<bf16><<<dim3(4096/128, NROWS/128, 1), blk, 0, stream>>>(
      ckvb, wkvbb, khv, 512, 512, 512, 4096, 4096, 0, 0, 0);
  tr_v<<<dim3(S_TOK/64, 2, 32), blk, 0, stream>>>(khv, vTb);
  // standard MHA flash attention (192-dim QK, 128-dim PV), 64-token tiles
  attn_mfma<<<dim3(1024), blk, 0, stream>>>(qbuf, khv, kpeb, vTb, obuf);
  // out = o @ wo^T (128-tile, f32 out)
  gemm128<float><<<dim3(2048/128, NROWS/128, 1), blk, 0, stream>>>(
      obuf, wob, out, 2048, 2048, 2048, 2048, 2048, 0, 0, 0);
}